// Round 11
// baseline (2343.389 us; speedup 1.0000x reference)
//
#include <hip/hip_runtime.h>
#include <hip/hip_bf16.h>
#include <cstddef>

#define N_NODES 10000
#define KTOP 30
#define CAP 2048     // max CSR row length
#define NBINS 4096
#define CANDCAP 512

// ---------------- fp32 GEMM: C[M,N] = op(A[M,K] @ B[K,N] + bias) ----------------
template<int RELU, int BIAS>
__global__ __launch_bounds__(256) void gemm_rect(const float* __restrict__ A,
                                                 const float* __restrict__ B,
                                                 const float* __restrict__ bias,
                                                 float* __restrict__ C,
                                                 int M, int N, int K) {
    __shared__ float As[16][132];
    __shared__ float Bs[16][64];
    int t = threadIdx.x;
    int tx = t & 15;
    int ty = t >> 4;
    int m0 = blockIdx.y * 128;
    int n0 = blockIdx.x * 64;
    float acc[8][4];
    for (int r = 0; r < 8; r++) {
        for (int c = 0; c < 4; c++) { acc[r][c] = 0.f; }
    }
    for (int k0 = 0; k0 < K; k0 += 16) {
        for (int i = 0; i < 8; i++) {
            int idx = t + i * 256;
            int m = idx >> 4;
            int k = idx & 15;
            int gm = m0 + m;
            float v = 0.f;
            if (gm < M) { v = A[(size_t)gm * K + k0 + k]; }
            As[k][m] = v;
        }
        for (int i = 0; i < 4; i++) {
            int idx = t + i * 256;
            int k = idx >> 6;
            int n = idx & 63;
            int gn = n0 + n;
            float v = 0.f;
            if (gn < N) { v = B[(size_t)(k0 + k) * N + gn]; }
            Bs[k][n] = v;
        }
        __syncthreads();
        for (int kk = 0; kk < 16; kk++) {
            float a[8];
            float b[4];
            #pragma unroll
            for (int r = 0; r < 8; r++) { a[r] = As[kk][ty * 8 + r]; }
            #pragma unroll
            for (int c = 0; c < 4; c++) { b[c] = Bs[kk][tx * 4 + c]; }
            #pragma unroll
            for (int r = 0; r < 8; r++) {
                #pragma unroll
                for (int c = 0; c < 4; c++) {
                    acc[r][c] = fmaf(a[r], b[c], acc[r][c]);
                }
            }
        }
        __syncthreads();
    }
    for (int r = 0; r < 8; r++) {
        int gm = m0 + ty * 8 + r;
        if (gm >= M) { continue; }
        for (int c = 0; c < 4; c++) {
            int gn = n0 + tx * 4 + c;
            if (gn >= N) { continue; }
            float v = acc[r][c];
            if (BIAS) { v += bias[gn]; }
            if (RELU) { v = fmaxf(v, 0.f); }
            C[(size_t)gm * N + gn] = v;
        }
    }
}

// ---------------- row normalize, numpy-pairwise-exact semantics ----------------
__global__ __launch_bounds__(256) void rownorm_np_kernel(float* __restrict__ h) {
    __shared__ float row[256];
    __shared__ float denom_sh;
    int r = blockIdx.x;
    int t = threadIdx.x;
    float* p = h + (size_t)r * 256;
    row[t] = p[t];
    __syncthreads();
    if (t == 0) {
        float res[2];
        for (int half = 0; half < 2; half++) {
            const float* a = row + half * 128;
            float rr[8];
            #pragma unroll
            for (int j = 0; j < 8; j++) {
                rr[j] = __fmul_rn(a[j], a[j]);
            }
            for (int i = 8; i < 128; i += 8) {
                #pragma unroll
                for (int j = 0; j < 8; j++) {
                    rr[j] = __fadd_rn(rr[j], __fmul_rn(a[i + j], a[i + j]));
                }
            }
            res[half] = __fadd_rn(
                __fadd_rn(__fadd_rn(rr[0], rr[1]), __fadd_rn(rr[2], rr[3])),
                __fadd_rn(__fadd_rn(rr[4], rr[5]), __fadd_rn(rr[6], rr[7])));
        }
        float tot = __fadd_rn(res[0], res[1]);
        denom_sh = __fadd_rn(__fsqrt_rn(tot), 1e-8f);
    }
    __syncthreads();
    p[t] = __fdiv_rn(row[t], denom_sh);
}

// ---------------- S tile GEMM (NT, symmetric): S[r,j]=S[j,r]=relu(hn[r].hn[j]) ----------------
// 128x128 tile, 256 threads, 8x8/thr. Lane->fragment mapping gives 8 distinct
// stride-8 LDS addresses per wave per operand = 2-way aliasing = conflict-free.
// Epilogue: both natural and mirrored tiles written as float4 stores.
__global__ __launch_bounds__(256) void gemm_s_kernel(const float* __restrict__ hn,
                                                     float* __restrict__ S) {
    int rb = blockIdx.y * 128;
    int cb = blockIdx.x * 128;
    if (cb < rb) { return; }
    __shared__ __align__(16) float As[16][132];
    __shared__ __align__(16) float Bs[16][132];
    int t = threadIdx.x;
    int w = t >> 6;
    int lane = t & 63;
    int colf = (lane & 7) + ((w & 1) << 3);    // 0..15
    int rowf = (lane >> 3) + ((w >> 1) << 3);  // 0..15
    float acc[8][8];
    for (int r = 0; r < 8; r++) {
        for (int c = 0; c < 8; c++) { acc[r][c] = 0.f; }
    }
    int m = t & 127;
    int c0 = t >> 7;
    for (int k0 = 0; k0 < 256; k0 += 16) {
        for (int it = 0; it < 2; it++) {
            int c = c0 + 2 * it;
            int gr = rb + m;
            if (gr > N_NODES - 1) { gr = N_NODES - 1; }
            float4 va = *(const float4*)(hn + (size_t)gr * 256 + k0 + 4 * c);
            As[4 * c + 0][m] = va.x;
            As[4 * c + 1][m] = va.y;
            As[4 * c + 2][m] = va.z;
            As[4 * c + 3][m] = va.w;
            int gc = cb + m;
            if (gc > N_NODES - 1) { gc = N_NODES - 1; }
            float4 vb = *(const float4*)(hn + (size_t)gc * 256 + k0 + 4 * c);
            Bs[4 * c + 0][m] = vb.x;
            Bs[4 * c + 1][m] = vb.y;
            Bs[4 * c + 2][m] = vb.z;
            Bs[4 * c + 3][m] = vb.w;
        }
        __syncthreads();
        for (int kk = 0; kk < 16; kk++) {
            float a[8];
            float b[8];
            *(float4*)&a[0] = *(const float4*)&As[kk][rowf * 8];
            *(float4*)&a[4] = *(const float4*)&As[kk][rowf * 8 + 4];
            *(float4*)&b[0] = *(const float4*)&Bs[kk][colf * 8];
            *(float4*)&b[4] = *(const float4*)&Bs[kk][colf * 8 + 4];
            #pragma unroll
            for (int r = 0; r < 8; r++) {
                #pragma unroll
                for (int c = 0; c < 8; c++) {
                    acc[r][c] = fmaf(a[r], b[c], acc[r][c]);
                }
            }
        }
        __syncthreads();
    }
    int rr0 = rb + rowf * 8;
    int cc0 = cb + colf * 8;
    // natural tile: rows rr0..rr0+7, cols cc0..cc0+7 (vectorized over c)
    for (int r = 0; r < 8; r++) {
        int rr = rr0 + r;
        if (rr >= N_NODES) { continue; }
        float v[8];
        #pragma unroll
        for (int c = 0; c < 8; c++) { v[c] = fmaxf(acc[r][c], 0.f); }
        if (cc0 + 7 < N_NODES) {
            float* dst = S + (size_t)rr * N_NODES + cc0;
            *(float4*)dst = *(float4*)&v[0];
            *(float4*)(dst + 4) = *(float4*)&v[4];
        } else {
            for (int c = 0; c < 8; c++) {
                int cc = cc0 + c;
                if (cc < N_NODES) { S[(size_t)rr * N_NODES + cc] = v[c]; }
            }
        }
    }
    // mirrored tile: rows cc0..cc0+7, cols rr0..rr0+7 (vectorized over r)
    for (int c = 0; c < 8; c++) {
        int cc = cc0 + c;
        if (cc >= N_NODES) { continue; }
        float v[8];
        #pragma unroll
        for (int r = 0; r < 8; r++) { v[r] = fmaxf(acc[r][c], 0.f); }
        if (rr0 + 7 < N_NODES) {
            float* dst = S + (size_t)cc * N_NODES + rr0;
            *(float4*)dst = *(float4*)&v[0];
            *(float4*)(dst + 4) = *(float4*)&v[4];
        } else {
            for (int r = 0; r < 8; r++) {
                int rr = rr0 + r;
                if (rr < N_NODES) { S[(size_t)cc * N_NODES + rr] = v[r]; }
            }
        }
    }
}

// ---------------- radix-select top-30 per row, ties -> HIGHEST index ----------------
// Row cached in LDS on first pass. Histogram skips zeros (bin-0 atomic storm).
// Rows with <KTOP positives or candidate overflow take the exact fallback.
__global__ __launch_bounds__(256) void topk_radix_kernel(const float* __restrict__ S,
                                                         float* __restrict__ tv,
                                                         int* __restrict__ ti) {
    __shared__ float sv[N_NODES];
    __shared__ int hist[NBINS];
    __shared__ int chunkSum[256];
    __shared__ float cv[CANDCAP];
    __shared__ int ci[CANDCAP];
    __shared__ int cntSh;
    __shared__ int thrSh;
    __shared__ float wv[4];
    __shared__ int wi[4];
    __shared__ int wq[4];
    int t = threadIdx.x;
    int r = blockIdx.x;
    const float* row = S + (size_t)r * N_NODES;

    for (int b = t; b < NBINS; b += 256) { hist[b] = 0; }
    if (t == 0) { cntSh = 0; }
    __syncthreads();

    // pass 1: global -> LDS copy + histogram of positives
    for (int j4 = t; j4 < N_NODES / 4; j4 += 256) {
        float4 v = *(const float4*)(row + 4 * j4);
        *(float4*)(sv + 4 * j4) = v;
        if (v.x > 0.f) { atomicAdd(&hist[__float_as_uint(v.x) >> 18], 1); }
        if (v.y > 0.f) { atomicAdd(&hist[__float_as_uint(v.y) >> 18], 1); }
        if (v.z > 0.f) { atomicAdd(&hist[__float_as_uint(v.z) >> 18], 1); }
        if (v.w > 0.f) { atomicAdd(&hist[__float_as_uint(v.w) >> 18], 1); }
    }
    __syncthreads();
    // suffix-count: find threshold bin T among positives
    int cs = 0;
    for (int b = 0; b < 16; b++) { cs += hist[t * 16 + b]; }
    chunkSum[t] = cs;
    __syncthreads();
    if (t == 0) {
        int npos = 0;
        for (int c = 0; c < 256; c++) { npos += chunkSum[c]; }
        if (npos < KTOP) {
            thrSh = -1;  // fallback
        } else {
            int cum = 0;
            int c = 255;
            for (; c >= 0; c--) {
                cum += chunkSum[c];
                if (cum >= KTOP) { break; }
            }
            int acc = cum - chunkSum[c];
            int T = c * 16;
            for (int b = c * 16 + 15; b >= c * 16; b--) {
                acc += hist[b];
                if (acc >= KTOP) { T = b; break; }
            }
            thrSh = T;
        }
    }
    __syncthreads();
    int T = thrSh;
    int ncand = 0;

    if (T >= 0) {
        // pass 2: collect candidates (positive, key >= T) from LDS
        for (int j = t; j < N_NODES; j += 256) {
            float v = sv[j];
            if (v > 0.f && (int)(__float_as_uint(v) >> 18) >= T) {
                int p = atomicAdd(&cntSh, 1);
                if (p < CANDCAP) {
                    cv[p] = v;
                    ci[p] = j;
                }
            }
        }
        __syncthreads();
        ncand = cntSh;
    }

    if (T < 0 || ncand > CANDCAP) {
        // exact fallback: iterative argmax over the LDS row
        for (int k = 0; k < KTOP; k++) {
            float bv = -1.f;
            int bi = -1;
            for (int j = t; j < N_NODES; j += 256) {
                float v = sv[j];
                if (v >= bv) { bv = v; bi = j; }
            }
            for (int off = 32; off > 0; off >>= 1) {
                float ov = __shfl_down(bv, off, 64);
                int oi = __shfl_down(bi, off, 64);
                if (ov > bv || (ov == bv && oi > bi)) { bv = ov; bi = oi; }
            }
            if ((t & 63) == 0) { wv[t >> 6] = bv; wi[t >> 6] = bi; }
            __syncthreads();
            if (t == 0) {
                float fv = wv[0];
                int fi = wi[0];
                for (int q = 1; q < 4; q++) {
                    if (wv[q] > fv || (wv[q] == fv && wi[q] > fi)) { fv = wv[q]; fi = wi[q]; }
                }
                tv[r * KTOP + k] = fv;
                ti[r * KTOP + k] = fi;
                sv[fi] = -1.f;
            }
            __syncthreads();
        }
        return;
    }

    // exact selection over candidates: (value desc, index desc)
    for (int k = 0; k < KTOP; k++) {
        float bv = -2.f;
        int bi = -1;
        int bq = -1;
        for (int q = t; q < ncand; q += 256) {
            float v = cv[q];
            int idx = ci[q];
            if (v > bv || (v == bv && idx > bi)) { bv = v; bi = idx; bq = q; }
        }
        for (int off = 32; off > 0; off >>= 1) {
            float ov = __shfl_down(bv, off, 64);
            int oi = __shfl_down(bi, off, 64);
            int oq = __shfl_down(bq, off, 64);
            if (ov > bv || (ov == bv && oi > bi)) { bv = ov; bi = oi; bq = oq; }
        }
        if ((t & 63) == 0) { wv[t >> 6] = bv; wi[t >> 6] = bi; wq[t >> 6] = bq; }
        __syncthreads();
        if (t == 0) {
            float fv = wv[0];
            int fi = wi[0];
            int fq = wq[0];
            for (int q = 1; q < 4; q++) {
                if (wv[q] > fv || (wv[q] == fv && wi[q] > fi)) {
                    fv = wv[q]; fi = wi[q]; fq = wq[q];
                }
            }
            tv[r * KTOP + k] = fv;
            ti[r * KTOP + k] = fi;
            cv[fq] = -2.f;
        }
        __syncthreads();
    }
}

// ---------------- degree accumulation ----------------
__global__ __launch_bounds__(256) void degree_kernel(const float* __restrict__ tv,
                                                     const int* __restrict__ ti,
                                                     float* __restrict__ deg) {
    int e = blockIdx.x * 256 + threadIdx.x;
    if (e >= N_NODES * KTOP) { return; }
    int i = e / KTOP;
    int j = ti[e];
    float v = 0.5f * tv[e];
    atomicAdd(deg + i, v);
    atomicAdd(deg + j, v);
}

__global__ __launch_bounds__(256) void dis_kernel(const float* __restrict__ deg,
                                                  float* __restrict__ dis) {
    int i = blockIdx.x * 256 + threadIdx.x;
    if (i < N_NODES) {
        float d = deg[i];
        dis[i] = d > 0.f ? 1.f / sqrtf(fmaxf(d, 1e-8f)) : 0.f;
    }
}

// ---------------- CSR build ----------------
__global__ __launch_bounds__(256) void csr_build(const float* __restrict__ tv,
                                                 const int* __restrict__ ti,
                                                 const float* __restrict__ dis,
                                                 int* __restrict__ cnt,
                                                 int* __restrict__ nbr,
                                                 float* __restrict__ wgt) {
    int e = blockIdx.x * 256 + threadIdx.x;
    if (e >= N_NODES * KTOP) { return; }
    int i = e / KTOP;
    int j = ti[e];
    float v = tv[e];
    float vrev = 0.f;
    bool mutual = false;
    const int* tj = ti + (size_t)j * KTOP;
    const float* tvj = tv + (size_t)j * KTOP;
    for (int k = 0; k < KTOP; k++) {
        if (tj[k] == i) { vrev = tvj[k]; mutual = true; }
    }
    float w = 0.5f * (v + vrev) * dis[i] * dis[j];
    int p = atomicAdd(cnt + i, 1);
    if (p < CAP) {
        nbr[(size_t)i * CAP + p] = j;
        wgt[(size_t)i * CAP + p] = w;
    }
    if (!mutual) {
        int p2 = atomicAdd(cnt + j, 1);
        if (p2 < CAP) {
            nbr[(size_t)j * CAP + p2] = i;
            wgt[(size_t)j * CAP + p2] = w;
        }
    }
}

// ---------------- gather SpMM, 128 channels, relu fused ----------------
__global__ __launch_bounds__(256) void gather128(const int* __restrict__ cnt,
                                                 const int* __restrict__ nbr,
                                                 const float* __restrict__ wgt,
                                                 const float* __restrict__ T,
                                                 float* __restrict__ Y) {
    int node = blockIdx.x * 2 + (threadIdx.x >> 7);
    int c = threadIdx.x & 127;
    if (node >= N_NODES) { return; }
    int n = cnt[node];
    if (n > CAP) { n = CAP; }
    const int* nb = nbr + (size_t)node * CAP;
    const float* wg = wgt + (size_t)node * CAP;
    float acc = 0.f;
    for (int k = 0; k < n; k++) {
        acc = fmaf(wg[k], T[(size_t)nb[k] * 128 + c], acc);
    }
    Y[(size_t)node * 128 + c] = fmaxf(acc, 0.f);
}

// ---------------- gather SpMM, 16 channels ----------------
__global__ __launch_bounds__(256) void gather16(const int* __restrict__ cnt,
                                                const int* __restrict__ nbr,
                                                const float* __restrict__ wgt,
                                                const float* __restrict__ T,
                                                float* __restrict__ Y) {
    int node = blockIdx.x * 16 + (threadIdx.x >> 4);
    int c = threadIdx.x & 15;
    if (node >= N_NODES) { return; }
    int n = cnt[node];
    if (n > CAP) { n = CAP; }
    const int* nb = nbr + (size_t)node * CAP;
    const float* wg = wgt + (size_t)node * CAP;
    float acc = 0.f;
    for (int k = 0; k < n; k++) {
        acc = fmaf(wg[k], T[(size_t)nb[k] * 16 + c], acc);
    }
    Y[(size_t)node * 16 + c] = acc;
}

// ---------------- Adj scatter (dense output) ----------------
__global__ __launch_bounds__(256) void adj_scatter(const float* __restrict__ tv,
                                                   const int* __restrict__ ti,
                                                   const float* __restrict__ dis,
                                                   float* __restrict__ Adj) {
    int e = blockIdx.x * 256 + threadIdx.x;
    if (e >= N_NODES * KTOP) { return; }
    int i = e / KTOP;
    int j = ti[e];
    float v = tv[e];
    float vrev = 0.f;
    const int* tj = ti + (size_t)j * KTOP;
    const float* tvj = tv + (size_t)j * KTOP;
    for (int k = 0; k < KTOP; k++) {
        if (tj[k] == i) { vrev = tvj[k]; }
    }
    float w = 0.5f * (v + vrev) * dis[i] * dis[j];
    Adj[(size_t)i * N_NODES + j] = w;
    Adj[(size_t)j * N_NODES + i] = w;
}

extern "C" void kernel_launch(void* const* d_in, const int* in_sizes, int n_in,
                              void* d_out, int out_size, void* d_ws, size_t ws_size,
                              hipStream_t stream) {
    const float* features = (const float*)d_in[0];
    const float* x   = (const float*)d_in[1];
    const float* W1  = (const float*)d_in[2];
    const float* W2  = (const float*)d_in[3];
    const float* Wg1 = (const float*)d_in[4];
    const float* bg1 = (const float*)d_in[5];
    const float* Wg2 = (const float*)d_in[6];
    const float* bg2 = (const float*)d_in[7];

    float* ws = (float*)d_ws;
    float* hbuf = ws;                         // 2,560,000 f
    float* htmp = ws + 2560000;               // 2,560,000 f
    float* tv   = ws + 5120000;               // 300,000 f
    int*   ti   = (int*)(ws + 5420000);       // 300,000 i
    float* deg  = ws + 5720000;               // 10,000 f
    float* dis  = ws + 5730000;               // 10,000 f
    float* t2   = ws + 5740000;               // 160,000 f
    int*   cnt  = (int*)(ws + 5900000);       // 10,000 i
    float* t1   = hbuf;                       // reuse
    float* y1   = htmp;                       // reuse

    float* out_f = (float*)d_out;             // 160,000 f32
    float* Adj   = out_f + 160000;            // 1e8 f32 = 400 MB
    float* Sbuf  = Adj;                       // S until topk
    int*   nbr   = (int*)Adj;                 // CSR neighbors 82 MB
    float* wgt   = (float*)(Adj + (size_t)N_NODES * CAP);  // CSR weights 82 MB

    // ---- fp32 MLP chain ----
    dim3 g1(4, 79);
    gemm_rect<1, 0><<<g1, dim3(256), 0, stream>>>(
        features, W1, (const float*)nullptr, htmp, N_NODES, 256, 256);
    gemm_rect<0, 0><<<g1, dim3(256), 0, stream>>>(
        htmp, W2, (const float*)nullptr, hbuf, N_NODES, 256, 256);
    rownorm_np_kernel<<<dim3(N_NODES), dim3(256), 0, stream>>>(hbuf);

    // ---- S (triangle + mirror), radix top-30 with highest-index ties ----
    gemm_s_kernel<<<dim3(79, 79), dim3(256), 0, stream>>>(hbuf, Sbuf);
    topk_radix_kernel<<<dim3(N_NODES), dim3(256), 0, stream>>>(Sbuf, tv, ti);

    // ---- degrees + normalization ----
    hipMemsetAsync(deg, 0, N_NODES * sizeof(float), stream);
    int eblocks = (N_NODES * KTOP + 255) / 256;
    degree_kernel<<<dim3(eblocks), dim3(256), 0, stream>>>(tv, ti, deg);
    dis_kernel<<<dim3((N_NODES + 255) / 256), dim3(256), 0, stream>>>(deg, dis);

    // ---- CSR build in the (dead) S/Adj region ----
    hipMemsetAsync(cnt, 0, N_NODES * sizeof(int), stream);
    csr_build<<<dim3(eblocks), dim3(256), 0, stream>>>(tv, ti, dis, cnt, nbr, wgt);

    // ---- GCN layers via gather SpMM ----
    gemm_rect<0, 1><<<dim3(2, 79), dim3(256), 0, stream>>>(
        x, Wg1, bg1, t1, N_NODES, 128, 256);
    gather128<<<dim3(N_NODES / 2), dim3(256), 0, stream>>>(cnt, nbr, wgt, t1, y1);
    gemm_rect<0, 1><<<dim3(1, 79), dim3(256), 0, stream>>>(
        y1, Wg2, bg2, t2, N_NODES, 16, 128);
    gather16<<<dim3((N_NODES + 15) / 16), dim3(256), 0, stream>>>(cnt, nbr, wgt, t2, out_f);

    // ---- dense Adj output last (overwrites CSR region) ----
    hipMemsetAsync(Adj, 0, (size_t)N_NODES * N_NODES * sizeof(float), stream);
    adj_scatter<<<dim3(eblocks), dim3(256), 0, stream>>>(tv, ti, dis, Adj);
}

// Round 12
// 1798.479 us; speedup vs baseline: 1.3030x; 1.3030x over previous
//
#include <hip/hip_runtime.h>
#include <hip/hip_bf16.h>
#include <cstddef>

#define N_NODES 10000
#define KTOP 30
#define CAP 2048     // max CSR row length
#define NBINS 4096
#define CANDCAP 512

// ---------------- fp32 GEMM: C[M,N] = op(A[M,K] @ B[K,N] + bias) ----------------
template<int RELU, int BIAS>
__global__ __launch_bounds__(256) void gemm_rect(const float* __restrict__ A,
                                                 const float* __restrict__ B,
                                                 const float* __restrict__ bias,
                                                 float* __restrict__ C,
                                                 int M, int N, int K) {
    __shared__ float As[16][132];
    __shared__ float Bs[16][64];
    int t = threadIdx.x;
    int tx = t & 15;
    int ty = t >> 4;
    int m0 = blockIdx.y * 128;
    int n0 = blockIdx.x * 64;
    float acc[8][4];
    for (int r = 0; r < 8; r++) {
        for (int c = 0; c < 4; c++) { acc[r][c] = 0.f; }
    }
    for (int k0 = 0; k0 < K; k0 += 16) {
        for (int i = 0; i < 8; i++) {
            int idx = t + i * 256;
            int m = idx >> 4;
            int k = idx & 15;
            int gm = m0 + m;
            float v = 0.f;
            if (gm < M) { v = A[(size_t)gm * K + k0 + k]; }
            As[k][m] = v;
        }
        for (int i = 0; i < 4; i++) {
            int idx = t + i * 256;
            int k = idx >> 6;
            int n = idx & 63;
            int gn = n0 + n;
            float v = 0.f;
            if (gn < N) { v = B[(size_t)(k0 + k) * N + gn]; }
            Bs[k][n] = v;
        }
        __syncthreads();
        for (int kk = 0; kk < 16; kk++) {
            float a[8];
            float b[4];
            #pragma unroll
            for (int r = 0; r < 8; r++) { a[r] = As[kk][ty * 8 + r]; }
            #pragma unroll
            for (int c = 0; c < 4; c++) { b[c] = Bs[kk][tx * 4 + c]; }
            #pragma unroll
            for (int r = 0; r < 8; r++) {
                #pragma unroll
                for (int c = 0; c < 4; c++) {
                    acc[r][c] = fmaf(a[r], b[c], acc[r][c]);
                }
            }
        }
        __syncthreads();
    }
    for (int r = 0; r < 8; r++) {
        int gm = m0 + ty * 8 + r;
        if (gm >= M) { continue; }
        for (int c = 0; c < 4; c++) {
            int gn = n0 + tx * 4 + c;
            if (gn >= N) { continue; }
            float v = acc[r][c];
            if (BIAS) { v += bias[gn]; }
            if (RELU) { v = fmaxf(v, 0.f); }
            C[(size_t)gm * N + gn] = v;
        }
    }
}

// ---------------- row normalize, numpy-pairwise-exact semantics ----------------
__global__ __launch_bounds__(256) void rownorm_np_kernel(float* __restrict__ h) {
    __shared__ float row[256];
    __shared__ float denom_sh;
    int r = blockIdx.x;
    int t = threadIdx.x;
    float* p = h + (size_t)r * 256;
    row[t] = p[t];
    __syncthreads();
    if (t == 0) {
        float res[2];
        for (int half = 0; half < 2; half++) {
            const float* a = row + half * 128;
            float rr[8];
            #pragma unroll
            for (int j = 0; j < 8; j++) {
                rr[j] = __fmul_rn(a[j], a[j]);
            }
            for (int i = 8; i < 128; i += 8) {
                #pragma unroll
                for (int j = 0; j < 8; j++) {
                    rr[j] = __fadd_rn(rr[j], __fmul_rn(a[i + j], a[i + j]));
                }
            }
            res[half] = __fadd_rn(
                __fadd_rn(__fadd_rn(rr[0], rr[1]), __fadd_rn(rr[2], rr[3])),
                __fadd_rn(__fadd_rn(rr[4], rr[5]), __fadd_rn(rr[6], rr[7])));
        }
        float tot = __fadd_rn(res[0], res[1]);
        denom_sh = __fadd_rn(__fsqrt_rn(tot), 1e-8f);
    }
    __syncthreads();
    p[t] = __fdiv_rn(row[t], denom_sh);
}

// ---------------- S tile GEMM (NT, symmetric): S[r,j]=S[j,r]=relu(hn[r].hn[j]) ----------------
// 128x128 tile, 256 threads, 8x8/thr. Lane->fragment mapping gives 8 distinct
// stride-8 LDS addresses per wave per operand = 2-way aliasing = conflict-free.
// Epilogue: both natural and mirrored tiles written as float4 stores.
__global__ __launch_bounds__(256) void gemm_s_kernel(const float* __restrict__ hn,
                                                     float* __restrict__ S) {
    int rb = blockIdx.y * 128;
    int cb = blockIdx.x * 128;
    if (cb < rb) { return; }
    __shared__ __align__(16) float As[16][132];
    __shared__ __align__(16) float Bs[16][132];
    int t = threadIdx.x;
    int w = t >> 6;
    int lane = t & 63;
    int colf = (lane & 7) + ((w & 1) << 3);    // 0..15
    int rowf = (lane >> 3) + ((w >> 1) << 3);  // 0..15
    float acc[8][8];
    for (int r = 0; r < 8; r++) {
        for (int c = 0; c < 8; c++) { acc[r][c] = 0.f; }
    }
    int m = t & 127;
    int c0 = t >> 7;
    for (int k0 = 0; k0 < 256; k0 += 16) {
        for (int it = 0; it < 2; it++) {
            int c = c0 + 2 * it;
            int gr = rb + m;
            if (gr > N_NODES - 1) { gr = N_NODES - 1; }
            float4 va = *(const float4*)(hn + (size_t)gr * 256 + k0 + 4 * c);
            As[4 * c + 0][m] = va.x;
            As[4 * c + 1][m] = va.y;
            As[4 * c + 2][m] = va.z;
            As[4 * c + 3][m] = va.w;
            int gc = cb + m;
            if (gc > N_NODES - 1) { gc = N_NODES - 1; }
            float4 vb = *(const float4*)(hn + (size_t)gc * 256 + k0 + 4 * c);
            Bs[4 * c + 0][m] = vb.x;
            Bs[4 * c + 1][m] = vb.y;
            Bs[4 * c + 2][m] = vb.z;
            Bs[4 * c + 3][m] = vb.w;
        }
        __syncthreads();
        for (int kk = 0; kk < 16; kk++) {
            float a[8];
            float b[8];
            *(float4*)&a[0] = *(const float4*)&As[kk][rowf * 8];
            *(float4*)&a[4] = *(const float4*)&As[kk][rowf * 8 + 4];
            *(float4*)&b[0] = *(const float4*)&Bs[kk][colf * 8];
            *(float4*)&b[4] = *(const float4*)&Bs[kk][colf * 8 + 4];
            #pragma unroll
            for (int r = 0; r < 8; r++) {
                #pragma unroll
                for (int c = 0; c < 8; c++) {
                    acc[r][c] = fmaf(a[r], b[c], acc[r][c]);
                }
            }
        }
        __syncthreads();
    }
    int rr0 = rb + rowf * 8;
    int cc0 = cb + colf * 8;
    // natural tile: rows rr0..rr0+7, cols cc0..cc0+7 (vectorized over c)
    for (int r = 0; r < 8; r++) {
        int rr = rr0 + r;
        if (rr >= N_NODES) { continue; }
        float v[8];
        #pragma unroll
        for (int c = 0; c < 8; c++) { v[c] = fmaxf(acc[r][c], 0.f); }
        if (cc0 + 7 < N_NODES) {
            float* dst = S + (size_t)rr * N_NODES + cc0;
            *(float4*)dst = *(float4*)&v[0];
            *(float4*)(dst + 4) = *(float4*)&v[4];
        } else {
            for (int c = 0; c < 8; c++) {
                int cc = cc0 + c;
                if (cc < N_NODES) { S[(size_t)rr * N_NODES + cc] = v[c]; }
            }
        }
    }
    // mirrored tile: rows cc0..cc0+7, cols rr0..rr0+7 (vectorized over r)
    for (int c = 0; c < 8; c++) {
        int cc = cc0 + c;
        if (cc >= N_NODES) { continue; }
        float v[8];
        #pragma unroll
        for (int r = 0; r < 8; r++) { v[r] = fmaxf(acc[r][c], 0.f); }
        if (rr0 + 7 < N_NODES) {
            float* dst = S + (size_t)cc * N_NODES + rr0;
            *(float4*)dst = *(float4*)&v[0];
            *(float4*)(dst + 4) = *(float4*)&v[4];
        } else {
            for (int r = 0; r < 8; r++) {
                int rr = rr0 + r;
                if (rr < N_NODES) { S[(size_t)cc * N_NODES + rr] = v[r]; }
            }
        }
    }
}

// ---------------- radix-select top-30 per row, ties -> HIGHEST index ----------------
// r10 structure (global reads both passes, ~21 KB LDS, high occupancy) + zero-skip
// in the histogram (removes the bin-0 same-address atomic storm).
// Rows with <KTOP positives or candidate overflow take the exact fallback.
__global__ __launch_bounds__(256) void topk_radix_kernel(float* __restrict__ S,
                                                         float* __restrict__ tv,
                                                         int* __restrict__ ti) {
    __shared__ int hist[NBINS];
    __shared__ int chunkSum[256];
    __shared__ float cv[CANDCAP];
    __shared__ int ci[CANDCAP];
    __shared__ int cntSh;
    __shared__ int thrSh;
    __shared__ float wv[4];
    __shared__ int wi[4];
    __shared__ int wq[4];
    int t = threadIdx.x;
    int r = blockIdx.x;
    float* row = S + (size_t)r * N_NODES;

    for (int b = t; b < NBINS; b += 256) { hist[b] = 0; }
    if (t == 0) { cntSh = 0; }
    __syncthreads();

    // pass 1: histogram of positives (zeros skipped)
    for (int j4 = t; j4 < N_NODES / 4; j4 += 256) {
        float4 v = *(const float4*)(row + 4 * j4);
        if (v.x > 0.f) { atomicAdd(&hist[__float_as_uint(v.x) >> 18], 1); }
        if (v.y > 0.f) { atomicAdd(&hist[__float_as_uint(v.y) >> 18], 1); }
        if (v.z > 0.f) { atomicAdd(&hist[__float_as_uint(v.z) >> 18], 1); }
        if (v.w > 0.f) { atomicAdd(&hist[__float_as_uint(v.w) >> 18], 1); }
    }
    __syncthreads();
    // suffix-count: find threshold bin T among positives
    int cs = 0;
    for (int b = 0; b < 16; b++) { cs += hist[t * 16 + b]; }
    chunkSum[t] = cs;
    __syncthreads();
    if (t == 0) {
        int npos = 0;
        for (int c = 0; c < 256; c++) { npos += chunkSum[c]; }
        if (npos < KTOP) {
            thrSh = -1;  // fallback
        } else {
            int cum = 0;
            int c = 255;
            for (; c >= 0; c--) {
                cum += chunkSum[c];
                if (cum >= KTOP) { break; }
            }
            int acc = cum - chunkSum[c];
            int T = c * 16;
            for (int b = c * 16 + 15; b >= c * 16; b--) {
                acc += hist[b];
                if (acc >= KTOP) { T = b; break; }
            }
            thrSh = T;
        }
    }
    __syncthreads();
    int T = thrSh;
    int ncand = 0;

    if (T >= 0) {
        // pass 2: collect candidates (positive, key >= T); row is L2-warm
        for (int j4 = t; j4 < N_NODES / 4; j4 += 256) {
            float4 v = *(const float4*)(row + 4 * j4);
            float vv[4];
            vv[0] = v.x; vv[1] = v.y; vv[2] = v.z; vv[3] = v.w;
            int base = 4 * j4;
            for (int q = 0; q < 4; q++) {
                if (vv[q] > 0.f && (int)(__float_as_uint(vv[q]) >> 18) >= T) {
                    int p = atomicAdd(&cntSh, 1);
                    if (p < CANDCAP) {
                        cv[p] = vv[q];
                        ci[p] = base + q;
                    }
                }
            }
        }
        __syncthreads();
        ncand = cntSh;
    }

    if (T < 0 || ncand > CANDCAP) {
        // exact fallback: iterative argmax over the global row (destructive; S dead after)
        for (int k = 0; k < KTOP; k++) {
            float bv = -1.f;
            int bi = -1;
            for (int j = t; j < N_NODES; j += 256) {
                float v = row[j];
                if (v >= bv) { bv = v; bi = j; }
            }
            for (int off = 32; off > 0; off >>= 1) {
                float ov = __shfl_down(bv, off, 64);
                int oi = __shfl_down(bi, off, 64);
                if (ov > bv || (ov == bv && oi > bi)) { bv = ov; bi = oi; }
            }
            if ((t & 63) == 0) { wv[t >> 6] = bv; wi[t >> 6] = bi; }
            __syncthreads();
            if (t == 0) {
                float fv = wv[0];
                int fi = wi[0];
                for (int q = 1; q < 4; q++) {
                    if (wv[q] > fv || (wv[q] == fv && wi[q] > fi)) { fv = wv[q]; fi = wi[q]; }
                }
                tv[r * KTOP + k] = fv;
                ti[r * KTOP + k] = fi;
                row[fi] = -1.f;
            }
            __syncthreads();
        }
        return;
    }

    // exact selection over candidates: (value desc, index desc)
    for (int k = 0; k < KTOP; k++) {
        float bv = -2.f;
        int bi = -1;
        int bq = -1;
        for (int q = t; q < ncand; q += 256) {
            float v = cv[q];
            int idx = ci[q];
            if (v > bv || (v == bv && idx > bi)) { bv = v; bi = idx; bq = q; }
        }
        for (int off = 32; off > 0; off >>= 1) {
            float ov = __shfl_down(bv, off, 64);
            int oi = __shfl_down(bi, off, 64);
            int oq = __shfl_down(bq, off, 64);
            if (ov > bv || (ov == bv && oi > bi)) { bv = ov; bi = oi; bq = oq; }
        }
        if ((t & 63) == 0) { wv[t >> 6] = bv; wi[t >> 6] = bi; wq[t >> 6] = bq; }
        __syncthreads();
        if (t == 0) {
            float fv = wv[0];
            int fi = wi[0];
            int fq = wq[0];
            for (int q = 1; q < 4; q++) {
                if (wv[q] > fv || (wv[q] == fv && wi[q] > fi)) {
                    fv = wv[q]; fi = wi[q]; fq = wq[q];
                }
            }
            tv[r * KTOP + k] = fv;
            ti[r * KTOP + k] = fi;
            cv[fq] = -2.f;
        }
        __syncthreads();
    }
}

// ---------------- degree accumulation ----------------
__global__ __launch_bounds__(256) void degree_kernel(const float* __restrict__ tv,
                                                     const int* __restrict__ ti,
                                                     float* __restrict__ deg) {
    int e = blockIdx.x * 256 + threadIdx.x;
    if (e >= N_NODES * KTOP) { return; }
    int i = e / KTOP;
    int j = ti[e];
    float v = 0.5f * tv[e];
    atomicAdd(deg + i, v);
    atomicAdd(deg + j, v);
}

__global__ __launch_bounds__(256) void dis_kernel(const float* __restrict__ deg,
                                                  float* __restrict__ dis) {
    int i = blockIdx.x * 256 + threadIdx.x;
    if (i < N_NODES) {
        float d = deg[i];
        dis[i] = d > 0.f ? 1.f / sqrtf(fmaxf(d, 1e-8f)) : 0.f;
    }
}

// ---------------- CSR build ----------------
__global__ __launch_bounds__(256) void csr_build(const float* __restrict__ tv,
                                                 const int* __restrict__ ti,
                                                 const float* __restrict__ dis,
                                                 int* __restrict__ cnt,
                                                 int* __restrict__ nbr,
                                                 float* __restrict__ wgt) {
    int e = blockIdx.x * 256 + threadIdx.x;
    if (e >= N_NODES * KTOP) { return; }
    int i = e / KTOP;
    int j = ti[e];
    float v = tv[e];
    float vrev = 0.f;
    bool mutual = false;
    const int* tj = ti + (size_t)j * KTOP;
    const float* tvj = tv + (size_t)j * KTOP;
    for (int k = 0; k < KTOP; k++) {
        if (tj[k] == i) { vrev = tvj[k]; mutual = true; }
    }
    float w = 0.5f * (v + vrev) * dis[i] * dis[j];
    int p = atomicAdd(cnt + i, 1);
    if (p < CAP) {
        nbr[(size_t)i * CAP + p] = j;
        wgt[(size_t)i * CAP + p] = w;
    }
    if (!mutual) {
        int p2 = atomicAdd(cnt + j, 1);
        if (p2 < CAP) {
            nbr[(size_t)j * CAP + p2] = i;
            wgt[(size_t)j * CAP + p2] = w;
        }
    }
}

// ---------------- gather SpMM, 128 channels, relu fused ----------------
__global__ __launch_bounds__(256) void gather128(const int* __restrict__ cnt,
                                                 const int* __restrict__ nbr,
                                                 const float* __restrict__ wgt,
                                                 const float* __restrict__ T,
                                                 float* __restrict__ Y) {
    int node = blockIdx.x * 2 + (threadIdx.x >> 7);
    int c = threadIdx.x & 127;
    if (node >= N_NODES) { return; }
    int n = cnt[node];
    if (n > CAP) { n = CAP; }
    const int* nb = nbr + (size_t)node * CAP;
    const float* wg = wgt + (size_t)node * CAP;
    float acc = 0.f;
    for (int k = 0; k < n; k++) {
        acc = fmaf(wg[k], T[(size_t)nb[k] * 128 + c], acc);
    }
    Y[(size_t)node * 128 + c] = fmaxf(acc, 0.f);
}

// ---------------- gather SpMM, 16 channels ----------------
__global__ __launch_bounds__(256) void gather16(const int* __restrict__ cnt,
                                                const int* __restrict__ nbr,
                                                const float* __restrict__ wgt,
                                                const float* __restrict__ T,
                                                float* __restrict__ Y) {
    int node = blockIdx.x * 16 + (threadIdx.x >> 4);
    int c = threadIdx.x & 15;
    if (node >= N_NODES) { return; }
    int n = cnt[node];
    if (n > CAP) { n = CAP; }
    const int* nb = nbr + (size_t)node * CAP;
    const float* wg = wgt + (size_t)node * CAP;
    float acc = 0.f;
    for (int k = 0; k < n; k++) {
        acc = fmaf(wg[k], T[(size_t)nb[k] * 16 + c], acc);
    }
    Y[(size_t)node * 16 + c] = acc;
}

// ---------------- Adj scatter (dense output) ----------------
__global__ __launch_bounds__(256) void adj_scatter(const float* __restrict__ tv,
                                                   const int* __restrict__ ti,
                                                   const float* __restrict__ dis,
                                                   float* __restrict__ Adj) {
    int e = blockIdx.x * 256 + threadIdx.x;
    if (e >= N_NODES * KTOP) { return; }
    int i = e / KTOP;
    int j = ti[e];
    float v = tv[e];
    float vrev = 0.f;
    const int* tj = ti + (size_t)j * KTOP;
    const float* tvj = tv + (size_t)j * KTOP;
    for (int k = 0; k < KTOP; k++) {
        if (tj[k] == i) { vrev = tvj[k]; }
    }
    float w = 0.5f * (v + vrev) * dis[i] * dis[j];
    Adj[(size_t)i * N_NODES + j] = w;
    Adj[(size_t)j * N_NODES + i] = w;
}

extern "C" void kernel_launch(void* const* d_in, const int* in_sizes, int n_in,
                              void* d_out, int out_size, void* d_ws, size_t ws_size,
                              hipStream_t stream) {
    const float* features = (const float*)d_in[0];
    const float* x   = (const float*)d_in[1];
    const float* W1  = (const float*)d_in[2];
    const float* W2  = (const float*)d_in[3];
    const float* Wg1 = (const float*)d_in[4];
    const float* bg1 = (const float*)d_in[5];
    const float* Wg2 = (const float*)d_in[6];
    const float* bg2 = (const float*)d_in[7];

    float* ws = (float*)d_ws;
    float* hbuf = ws;                         // 2,560,000 f
    float* htmp = ws + 2560000;               // 2,560,000 f
    float* tv   = ws + 5120000;               // 300,000 f
    int*   ti   = (int*)(ws + 5420000);       // 300,000 i
    float* deg  = ws + 5720000;               // 10,000 f
    float* dis  = ws + 5730000;               // 10,000 f
    float* t2   = ws + 5740000;               // 160,000 f
    int*   cnt  = (int*)(ws + 5900000);       // 10,000 i
    float* t1   = hbuf;                       // reuse
    float* y1   = htmp;                       // reuse

    float* out_f = (float*)d_out;             // 160,000 f32
    float* Adj   = out_f + 160000;            // 1e8 f32 = 400 MB
    float* Sbuf  = Adj;                       // S until topk
    int*   nbr   = (int*)Adj;                 // CSR neighbors 82 MB
    float* wgt   = (float*)(Adj + (size_t)N_NODES * CAP);  // CSR weights 82 MB

    // ---- fp32 MLP chain ----
    dim3 g1(4, 79);
    gemm_rect<1, 0><<<g1, dim3(256), 0, stream>>>(
        features, W1, (const float*)nullptr, htmp, N_NODES, 256, 256);
    gemm_rect<0, 0><<<g1, dim3(256), 0, stream>>>(
        htmp, W2, (const float*)nullptr, hbuf, N_NODES, 256, 256);
    rownorm_np_kernel<<<dim3(N_NODES), dim3(256), 0, stream>>>(hbuf);

    // ---- S (triangle + mirror), radix top-30 with highest-index ties ----
    gemm_s_kernel<<<dim3(79, 79), dim3(256), 0, stream>>>(hbuf, Sbuf);
    topk_radix_kernel<<<dim3(N_NODES), dim3(256), 0, stream>>>(Sbuf, tv, ti);

    // ---- degrees + normalization ----
    hipMemsetAsync(deg, 0, N_NODES * sizeof(float), stream);
    int eblocks = (N_NODES * KTOP + 255) / 256;
    degree_kernel<<<dim3(eblocks), dim3(256), 0, stream>>>(tv, ti, deg);
    dis_kernel<<<dim3((N_NODES + 255) / 256), dim3(256), 0, stream>>>(deg, dis);

    // ---- CSR build in the (dead) S/Adj region ----
    hipMemsetAsync(cnt, 0, N_NODES * sizeof(int), stream);
    csr_build<<<dim3(eblocks), dim3(256), 0, stream>>>(tv, ti, dis, cnt, nbr, wgt);

    // ---- GCN layers via gather SpMM ----
    gemm_rect<0, 1><<<dim3(2, 79), dim3(256), 0, stream>>>(
        x, Wg1, bg1, t1, N_NODES, 128, 256);
    gather128<<<dim3(N_NODES / 2), dim3(256), 0, stream>>>(cnt, nbr, wgt, t1, y1);
    gemm_rect<0, 1><<<dim3(1, 79), dim3(256), 0, stream>>>(
        y1, Wg2, bg2, t2, N_NODES, 16, 128);
    gather16<<<dim3((N_NODES + 15) / 16), dim3(256), 0, stream>>>(cnt, nbr, wgt, t2, out_f);

    // ---- dense Adj output last (overwrites CSR region) ----
    hipMemsetAsync(Adj, 0, (size_t)N_NODES * N_NODES * sizeof(float), stream);
    adj_scatter<<<dim3(eblocks), dim3(256), 0, stream>>>(tv, ti, dis, Adj);
}

// Round 13
// 1766.586 us; speedup vs baseline: 1.3265x; 1.0181x over previous
//
#include <hip/hip_runtime.h>
#include <hip/hip_bf16.h>
#include <cstddef>

#define N_NODES 10000
#define KTOP 30
#define CAP 2048     // max CSR row length
#define NBINS 4096
#define CANDCAP 512
#define NQ4 (N_NODES / 4)   // 2500 float4 per row

// ---------------- fp32 GEMM: C[M,N] = op(A[M,K] @ B[K,N] + bias) ----------------
template<int RELU, int BIAS>
__global__ __launch_bounds__(256) void gemm_rect(const float* __restrict__ A,
                                                 const float* __restrict__ B,
                                                 const float* __restrict__ bias,
                                                 float* __restrict__ C,
                                                 int M, int N, int K) {
    __shared__ float As[16][132];
    __shared__ float Bs[16][64];
    int t = threadIdx.x;
    int tx = t & 15;
    int ty = t >> 4;
    int m0 = blockIdx.y * 128;
    int n0 = blockIdx.x * 64;
    float acc[8][4];
    for (int r = 0; r < 8; r++) {
        for (int c = 0; c < 4; c++) { acc[r][c] = 0.f; }
    }
    for (int k0 = 0; k0 < K; k0 += 16) {
        for (int i = 0; i < 8; i++) {
            int idx = t + i * 256;
            int m = idx >> 4;
            int k = idx & 15;
            int gm = m0 + m;
            float v = 0.f;
            if (gm < M) { v = A[(size_t)gm * K + k0 + k]; }
            As[k][m] = v;
        }
        for (int i = 0; i < 4; i++) {
            int idx = t + i * 256;
            int k = idx >> 6;
            int n = idx & 63;
            int gn = n0 + n;
            float v = 0.f;
            if (gn < N) { v = B[(size_t)(k0 + k) * N + gn]; }
            Bs[k][n] = v;
        }
        __syncthreads();
        for (int kk = 0; kk < 16; kk++) {
            float a[8];
            float b[4];
            #pragma unroll
            for (int r = 0; r < 8; r++) { a[r] = As[kk][ty * 8 + r]; }
            #pragma unroll
            for (int c = 0; c < 4; c++) { b[c] = Bs[kk][tx * 4 + c]; }
            #pragma unroll
            for (int r = 0; r < 8; r++) {
                #pragma unroll
                for (int c = 0; c < 4; c++) {
                    acc[r][c] = fmaf(a[r], b[c], acc[r][c]);
                }
            }
        }
        __syncthreads();
    }
    for (int r = 0; r < 8; r++) {
        int gm = m0 + ty * 8 + r;
        if (gm >= M) { continue; }
        for (int c = 0; c < 4; c++) {
            int gn = n0 + tx * 4 + c;
            if (gn >= N) { continue; }
            float v = acc[r][c];
            if (BIAS) { v += bias[gn]; }
            if (RELU) { v = fmaxf(v, 0.f); }
            C[(size_t)gm * N + gn] = v;
        }
    }
}

// ---------------- row normalize, numpy-pairwise-exact semantics ----------------
__global__ __launch_bounds__(256) void rownorm_np_kernel(float* __restrict__ h) {
    __shared__ float row[256];
    __shared__ float denom_sh;
    int r = blockIdx.x;
    int t = threadIdx.x;
    float* p = h + (size_t)r * 256;
    row[t] = p[t];
    __syncthreads();
    if (t == 0) {
        float res[2];
        for (int half = 0; half < 2; half++) {
            const float* a = row + half * 128;
            float rr[8];
            #pragma unroll
            for (int j = 0; j < 8; j++) {
                rr[j] = __fmul_rn(a[j], a[j]);
            }
            for (int i = 8; i < 128; i += 8) {
                #pragma unroll
                for (int j = 0; j < 8; j++) {
                    rr[j] = __fadd_rn(rr[j], __fmul_rn(a[i + j], a[i + j]));
                }
            }
            res[half] = __fadd_rn(
                __fadd_rn(__fadd_rn(rr[0], rr[1]), __fadd_rn(rr[2], rr[3])),
                __fadd_rn(__fadd_rn(rr[4], rr[5]), __fadd_rn(rr[6], rr[7])));
        }
        float tot = __fadd_rn(res[0], res[1]);
        denom_sh = __fadd_rn(__fsqrt_rn(tot), 1e-8f);
    }
    __syncthreads();
    p[t] = __fdiv_rn(row[t], denom_sh);
}

// ---------------- S tile GEMM (NT, symmetric): S[r,j]=S[j,r]=relu(hn[r].hn[j]) ----------------
__global__ __launch_bounds__(256) void gemm_s_kernel(const float* __restrict__ hn,
                                                     float* __restrict__ S) {
    int rb = blockIdx.y * 128;
    int cb = blockIdx.x * 128;
    if (cb < rb) { return; }
    __shared__ __align__(16) float As[16][132];
    __shared__ __align__(16) float Bs[16][132];
    int t = threadIdx.x;
    int w = t >> 6;
    int lane = t & 63;
    int colf = (lane & 7) + ((w & 1) << 3);    // 0..15
    int rowf = (lane >> 3) + ((w >> 1) << 3);  // 0..15
    float acc[8][8];
    for (int r = 0; r < 8; r++) {
        for (int c = 0; c < 8; c++) { acc[r][c] = 0.f; }
    }
    int m = t & 127;
    int c0 = t >> 7;
    for (int k0 = 0; k0 < 256; k0 += 16) {
        for (int it = 0; it < 2; it++) {
            int c = c0 + 2 * it;
            int gr = rb + m;
            if (gr > N_NODES - 1) { gr = N_NODES - 1; }
            float4 va = *(const float4*)(hn + (size_t)gr * 256 + k0 + 4 * c);
            As[4 * c + 0][m] = va.x;
            As[4 * c + 1][m] = va.y;
            As[4 * c + 2][m] = va.z;
            As[4 * c + 3][m] = va.w;
            int gc = cb + m;
            if (gc > N_NODES - 1) { gc = N_NODES - 1; }
            float4 vb = *(const float4*)(hn + (size_t)gc * 256 + k0 + 4 * c);
            Bs[4 * c + 0][m] = vb.x;
            Bs[4 * c + 1][m] = vb.y;
            Bs[4 * c + 2][m] = vb.z;
            Bs[4 * c + 3][m] = vb.w;
        }
        __syncthreads();
        for (int kk = 0; kk < 16; kk++) {
            float a[8];
            float b[8];
            *(float4*)&a[0] = *(const float4*)&As[kk][rowf * 8];
            *(float4*)&a[4] = *(const float4*)&As[kk][rowf * 8 + 4];
            *(float4*)&b[0] = *(const float4*)&Bs[kk][colf * 8];
            *(float4*)&b[4] = *(const float4*)&Bs[kk][colf * 8 + 4];
            #pragma unroll
            for (int r = 0; r < 8; r++) {
                #pragma unroll
                for (int c = 0; c < 8; c++) {
                    acc[r][c] = fmaf(a[r], b[c], acc[r][c]);
                }
            }
        }
        __syncthreads();
    }
    int rr0 = rb + rowf * 8;
    int cc0 = cb + colf * 8;
    for (int r = 0; r < 8; r++) {
        int rr = rr0 + r;
        if (rr >= N_NODES) { continue; }
        float v[8];
        #pragma unroll
        for (int c = 0; c < 8; c++) { v[c] = fmaxf(acc[r][c], 0.f); }
        if (cc0 + 7 < N_NODES) {
            float* dst = S + (size_t)rr * N_NODES + cc0;
            *(float4*)dst = *(float4*)&v[0];
            *(float4*)(dst + 4) = *(float4*)&v[4];
        } else {
            for (int c = 0; c < 8; c++) {
                int cc = cc0 + c;
                if (cc < N_NODES) { S[(size_t)rr * N_NODES + cc] = v[c]; }
            }
        }
    }
    for (int c = 0; c < 8; c++) {
        int cc = cc0 + c;
        if (cc >= N_NODES) { continue; }
        float v[8];
        #pragma unroll
        for (int r = 0; r < 8; r++) { v[r] = fmaxf(acc[r][c], 0.f); }
        if (rr0 + 7 < N_NODES) {
            float* dst = S + (size_t)cc * N_NODES + rr0;
            *(float4*)dst = *(float4*)&v[0];
            *(float4*)(dst + 4) = *(float4*)&v[4];
        } else {
            for (int r = 0; r < 8; r++) {
                int rr = rr0 + r;
                if (rr < N_NODES) { S[(size_t)cc * N_NODES + rr] = v[r]; }
            }
        }
    }
}

// ---------------- radix-select top-30 per row, ties -> HIGHEST index ----------------
// r12 structure + 5-deep load batching in both passes (5 outstanding vmcnt per wave
// instead of 1 -> hides ~900cyc HBM latency). Selection semantics unchanged.
__global__ __launch_bounds__(256) void topk_radix_kernel(float* __restrict__ S,
                                                         float* __restrict__ tv,
                                                         int* __restrict__ ti) {
    __shared__ int hist[NBINS];
    __shared__ int chunkSum[256];
    __shared__ float cv[CANDCAP];
    __shared__ int ci[CANDCAP];
    __shared__ int cntSh;
    __shared__ int thrSh;
    __shared__ float wv[4];
    __shared__ int wi[4];
    __shared__ int wq[4];
    int t = threadIdx.x;
    int r = blockIdx.x;
    float* row = S + (size_t)r * N_NODES;

    for (int b = t; b < NBINS; b += 256) { hist[b] = 0; }
    if (t == 0) { cntSh = 0; }
    __syncthreads();

    // pass 1: histogram of positives, two 5-deep load batches
    {
        float4 vv[5];
        // batch A: j4 = t + {0..4}*256 (max 1279 < 2500, no guard)
        #pragma unroll
        for (int u = 0; u < 5; u++) {
            vv[u] = *(const float4*)(row + 4 * (t + u * 256));
        }
        #pragma unroll
        for (int u = 0; u < 5; u++) {
            float4 v = vv[u];
            if (v.x > 0.f) { atomicAdd(&hist[__float_as_uint(v.x) >> 18], 1); }
            if (v.y > 0.f) { atomicAdd(&hist[__float_as_uint(v.y) >> 18], 1); }
            if (v.z > 0.f) { atomicAdd(&hist[__float_as_uint(v.z) >> 18], 1); }
            if (v.w > 0.f) { atomicAdd(&hist[__float_as_uint(v.w) >> 18], 1); }
        }
        // batch B: j4 = t + {5..9}*256 (guard: up to 2559 >= 2500)
        int ok[5];
        #pragma unroll
        for (int u = 0; u < 5; u++) {
            int j4 = t + (u + 5) * 256;
            ok[u] = j4 < NQ4;
            int jc = ok[u] ? j4 : (NQ4 - 1);
            vv[u] = *(const float4*)(row + 4 * jc);
        }
        #pragma unroll
        for (int u = 0; u < 5; u++) {
            if (!ok[u]) { continue; }
            float4 v = vv[u];
            if (v.x > 0.f) { atomicAdd(&hist[__float_as_uint(v.x) >> 18], 1); }
            if (v.y > 0.f) { atomicAdd(&hist[__float_as_uint(v.y) >> 18], 1); }
            if (v.z > 0.f) { atomicAdd(&hist[__float_as_uint(v.z) >> 18], 1); }
            if (v.w > 0.f) { atomicAdd(&hist[__float_as_uint(v.w) >> 18], 1); }
        }
    }
    __syncthreads();
    // suffix-count: find threshold bin T among positives
    int cs = 0;
    for (int b = 0; b < 16; b++) { cs += hist[t * 16 + b]; }
    chunkSum[t] = cs;
    __syncthreads();
    if (t == 0) {
        int npos = 0;
        for (int c = 0; c < 256; c++) { npos += chunkSum[c]; }
        if (npos < KTOP) {
            thrSh = -1;  // fallback
        } else {
            int cum = 0;
            int c = 255;
            for (; c >= 0; c--) {
                cum += chunkSum[c];
                if (cum >= KTOP) { break; }
            }
            int acc = cum - chunkSum[c];
            int T = c * 16;
            for (int b = c * 16 + 15; b >= c * 16; b--) {
                acc += hist[b];
                if (acc >= KTOP) { T = b; break; }
            }
            thrSh = T;
        }
    }
    __syncthreads();
    int T = thrSh;
    int ncand = 0;

    if (T >= 0) {
        // pass 2: collect candidates (positive, key >= T); 5-deep batches, L2-warm
        float4 vv[5];
        #pragma unroll
        for (int u = 0; u < 5; u++) {
            vv[u] = *(const float4*)(row + 4 * (t + u * 256));
        }
        #pragma unroll
        for (int u = 0; u < 5; u++) {
            float4 v = vv[u];
            int base = 4 * (t + u * 256);
            float vq[4];
            vq[0] = v.x; vq[1] = v.y; vq[2] = v.z; vq[3] = v.w;
            #pragma unroll
            for (int q = 0; q < 4; q++) {
                if (vq[q] > 0.f && (int)(__float_as_uint(vq[q]) >> 18) >= T) {
                    int p = atomicAdd(&cntSh, 1);
                    if (p < CANDCAP) {
                        cv[p] = vq[q];
                        ci[p] = base + q;
                    }
                }
            }
        }
        int ok[5];
        #pragma unroll
        for (int u = 0; u < 5; u++) {
            int j4 = t + (u + 5) * 256;
            ok[u] = j4 < NQ4;
            int jc = ok[u] ? j4 : (NQ4 - 1);
            vv[u] = *(const float4*)(row + 4 * jc);
        }
        #pragma unroll
        for (int u = 0; u < 5; u++) {
            if (!ok[u]) { continue; }
            float4 v = vv[u];
            int base = 4 * (t + (u + 5) * 256);
            float vq[4];
            vq[0] = v.x; vq[1] = v.y; vq[2] = v.z; vq[3] = v.w;
            #pragma unroll
            for (int q = 0; q < 4; q++) {
                if (vq[q] > 0.f && (int)(__float_as_uint(vq[q]) >> 18) >= T) {
                    int p = atomicAdd(&cntSh, 1);
                    if (p < CANDCAP) {
                        cv[p] = vq[q];
                        ci[p] = base + q;
                    }
                }
            }
        }
        __syncthreads();
        ncand = cntSh;
    }

    if (T < 0 || ncand > CANDCAP) {
        // exact fallback: iterative argmax over the global row (destructive; S dead after)
        for (int k = 0; k < KTOP; k++) {
            float bv = -1.f;
            int bi = -1;
            for (int j = t; j < N_NODES; j += 256) {
                float v = row[j];
                if (v >= bv) { bv = v; bi = j; }
            }
            for (int off = 32; off > 0; off >>= 1) {
                float ov = __shfl_down(bv, off, 64);
                int oi = __shfl_down(bi, off, 64);
                if (ov > bv || (ov == bv && oi > bi)) { bv = ov; bi = oi; }
            }
            if ((t & 63) == 0) { wv[t >> 6] = bv; wi[t >> 6] = bi; }
            __syncthreads();
            if (t == 0) {
                float fv = wv[0];
                int fi = wi[0];
                for (int q = 1; q < 4; q++) {
                    if (wv[q] > fv || (wv[q] == fv && wi[q] > fi)) { fv = wv[q]; fi = wi[q]; }
                }
                tv[r * KTOP + k] = fv;
                ti[r * KTOP + k] = fi;
                row[fi] = -1.f;
            }
            __syncthreads();
        }
        return;
    }

    // exact selection over candidates: (value desc, index desc)
    for (int k = 0; k < KTOP; k++) {
        float bv = -2.f;
        int bi = -1;
        int bq = -1;
        for (int q = t; q < ncand; q += 256) {
            float v = cv[q];
            int idx = ci[q];
            if (v > bv || (v == bv && idx > bi)) { bv = v; bi = idx; bq = q; }
        }
        for (int off = 32; off > 0; off >>= 1) {
            float ov = __shfl_down(bv, off, 64);
            int oi = __shfl_down(bi, off, 64);
            int oq = __shfl_down(bq, off, 64);
            if (ov > bv || (ov == bv && oi > bi)) { bv = ov; bi = oi; bq = oq; }
        }
        if ((t & 63) == 0) { wv[t >> 6] = bv; wi[t >> 6] = bi; wq[t >> 6] = bq; }
        __syncthreads();
        if (t == 0) {
            float fv = wv[0];
            int fi = wi[0];
            int fq = wq[0];
            for (int q = 1; q < 4; q++) {
                if (wv[q] > fv || (wv[q] == fv && wi[q] > fi)) {
                    fv = wv[q]; fi = wi[q]; fq = wq[q];
                }
            }
            tv[r * KTOP + k] = fv;
            ti[r * KTOP + k] = fi;
            cv[fq] = -2.f;
        }
        __syncthreads();
    }
}

// ---------------- degree accumulation ----------------
__global__ __launch_bounds__(256) void degree_kernel(const float* __restrict__ tv,
                                                     const int* __restrict__ ti,
                                                     float* __restrict__ deg) {
    int e = blockIdx.x * 256 + threadIdx.x;
    if (e >= N_NODES * KTOP) { return; }
    int i = e / KTOP;
    int j = ti[e];
    float v = 0.5f * tv[e];
    atomicAdd(deg + i, v);
    atomicAdd(deg + j, v);
}

__global__ __launch_bounds__(256) void dis_kernel(const float* __restrict__ deg,
                                                  float* __restrict__ dis) {
    int i = blockIdx.x * 256 + threadIdx.x;
    if (i < N_NODES) {
        float d = deg[i];
        dis[i] = d > 0.f ? 1.f / sqrtf(fmaxf(d, 1e-8f)) : 0.f;
    }
}

// ---------------- CSR build ----------------
__global__ __launch_bounds__(256) void csr_build(const float* __restrict__ tv,
                                                 const int* __restrict__ ti,
                                                 const float* __restrict__ dis,
                                                 int* __restrict__ cnt,
                                                 int* __restrict__ nbr,
                                                 float* __restrict__ wgt) {
    int e = blockIdx.x * 256 + threadIdx.x;
    if (e >= N_NODES * KTOP) { return; }
    int i = e / KTOP;
    int j = ti[e];
    float v = tv[e];
    float vrev = 0.f;
    bool mutual = false;
    const int* tj = ti + (size_t)j * KTOP;
    const float* tvj = tv + (size_t)j * KTOP;
    for (int k = 0; k < KTOP; k++) {
        if (tj[k] == i) { vrev = tvj[k]; mutual = true; }
    }
    float w = 0.5f * (v + vrev) * dis[i] * dis[j];
    int p = atomicAdd(cnt + i, 1);
    if (p < CAP) {
        nbr[(size_t)i * CAP + p] = j;
        wgt[(size_t)i * CAP + p] = w;
    }
    if (!mutual) {
        int p2 = atomicAdd(cnt + j, 1);
        if (p2 < CAP) {
            nbr[(size_t)j * CAP + p2] = i;
            wgt[(size_t)j * CAP + p2] = w;
        }
    }
}

// ---------------- gather SpMM, 128 channels, relu fused ----------------
__global__ __launch_bounds__(256) void gather128(const int* __restrict__ cnt,
                                                 const int* __restrict__ nbr,
                                                 const float* __restrict__ wgt,
                                                 const float* __restrict__ T,
                                                 float* __restrict__ Y) {
    int node = blockIdx.x * 2 + (threadIdx.x >> 7);
    int c = threadIdx.x & 127;
    if (node >= N_NODES) { return; }
    int n = cnt[node];
    if (n > CAP) { n = CAP; }
    const int* nb = nbr + (size_t)node * CAP;
    const float* wg = wgt + (size_t)node * CAP;
    float acc = 0.f;
    for (int k = 0; k < n; k++) {
        acc = fmaf(wg[k], T[(size_t)nb[k] * 128 + c], acc);
    }
    Y[(size_t)node * 128 + c] = fmaxf(acc, 0.f);
}

// ---------------- gather SpMM, 16 channels ----------------
__global__ __launch_bounds__(256) void gather16(const int* __restrict__ cnt,
                                                const int* __restrict__ nbr,
                                                const float* __restrict__ wgt,
                                                const float* __restrict__ T,
                                                float* __restrict__ Y) {
    int node = blockIdx.x * 16 + (threadIdx.x >> 4);
    int c = threadIdx.x & 15;
    if (node >= N_NODES) { return; }
    int n = cnt[node];
    if (n > CAP) { n = CAP; }
    const int* nb = nbr + (size_t)node * CAP;
    const float* wg = wgt + (size_t)node * CAP;
    float acc = 0.f;
    for (int k = 0; k < n; k++) {
        acc = fmaf(wg[k], T[(size_t)nb[k] * 16 + c], acc);
    }
    Y[(size_t)node * 16 + c] = acc;
}

// ---------------- Adj scatter (dense output) ----------------
__global__ __launch_bounds__(256) void adj_scatter(const float* __restrict__ tv,
                                                   const int* __restrict__ ti,
                                                   const float* __restrict__ dis,
                                                   float* __restrict__ Adj) {
    int e = blockIdx.x * 256 + threadIdx.x;
    if (e >= N_NODES * KTOP) { return; }
    int i = e / KTOP;
    int j = ti[e];
    float v = tv[e];
    float vrev = 0.f;
    const int* tj = ti + (size_t)j * KTOP;
    const float* tvj = tv + (size_t)j * KTOP;
    for (int k = 0; k < KTOP; k++) {
        if (tj[k] == i) { vrev = tvj[k]; }
    }
    float w = 0.5f * (v + vrev) * dis[i] * dis[j];
    Adj[(size_t)i * N_NODES + j] = w;
    Adj[(size_t)j * N_NODES + i] = w;
}

extern "C" void kernel_launch(void* const* d_in, const int* in_sizes, int n_in,
                              void* d_out, int out_size, void* d_ws, size_t ws_size,
                              hipStream_t stream) {
    const float* features = (const float*)d_in[0];
    const float* x   = (const float*)d_in[1];
    const float* W1  = (const float*)d_in[2];
    const float* W2  = (const float*)d_in[3];
    const float* Wg1 = (const float*)d_in[4];
    const float* bg1 = (const float*)d_in[5];
    const float* Wg2 = (const float*)d_in[6];
    const float* bg2 = (const float*)d_in[7];

    float* ws = (float*)d_ws;
    float* hbuf = ws;                         // 2,560,000 f
    float* htmp = ws + 2560000;               // 2,560,000 f
    float* tv   = ws + 5120000;               // 300,000 f
    int*   ti   = (int*)(ws + 5420000);       // 300,000 i
    float* deg  = ws + 5720000;               // 10,000 f
    float* dis  = ws + 5730000;               // 10,000 f
    float* t2   = ws + 5740000;               // 160,000 f
    int*   cnt  = (int*)(ws + 5900000);       // 10,000 i
    float* t1   = hbuf;                       // reuse
    float* y1   = htmp;                       // reuse

    float* out_f = (float*)d_out;             // 160,000 f32
    float* Adj   = out_f + 160000;            // 1e8 f32 = 400 MB
    float* Sbuf  = Adj;                       // S until topk
    int*   nbr   = (int*)Adj;                 // CSR neighbors 82 MB
    float* wgt   = (float*)(Adj + (size_t)N_NODES * CAP);  // CSR weights 82 MB

    // ---- fp32 MLP chain ----
    dim3 g1(4, 79);
    gemm_rect<1, 0><<<g1, dim3(256), 0, stream>>>(
        features, W1, (const float*)nullptr, htmp, N_NODES, 256, 256);
    gemm_rect<0, 0><<<g1, dim3(256), 0, stream>>>(
        htmp, W2, (const float*)nullptr, hbuf, N_NODES, 256, 256);
    rownorm_np_kernel<<<dim3(N_NODES), dim3(256), 0, stream>>>(hbuf);

    // ---- S (triangle + mirror), radix top-30 with highest-index ties ----
    gemm_s_kernel<<<dim3(79, 79), dim3(256), 0, stream>>>(hbuf, Sbuf);
    topk_radix_kernel<<<dim3(N_NODES), dim3(256), 0, stream>>>(Sbuf, tv, ti);

    // ---- degrees + normalization ----
    hipMemsetAsync(deg, 0, N_NODES * sizeof(float), stream);
    int eblocks = (N_NODES * KTOP + 255) / 256;
    degree_kernel<<<dim3(eblocks), dim3(256), 0, stream>>>(tv, ti, deg);
    dis_kernel<<<dim3((N_NODES + 255) / 256), dim3(256), 0, stream>>>(deg, dis);

    // ---- CSR build in the (dead) S/Adj region ----
    hipMemsetAsync(cnt, 0, N_NODES * sizeof(int), stream);
    csr_build<<<dim3(eblocks), dim3(256), 0, stream>>>(tv, ti, dis, cnt, nbr, wgt);

    // ---- GCN layers via gather SpMM ----
    gemm_rect<0, 1><<<dim3(2, 79), dim3(256), 0, stream>>>(
        x, Wg1, bg1, t1, N_NODES, 128, 256);
    gather128<<<dim3(N_NODES / 2), dim3(256), 0, stream>>>(cnt, nbr, wgt, t1, y1);
    gemm_rect<0, 1><<<dim3(1, 79), dim3(256), 0, stream>>>(
        y1, Wg2, bg2, t2, N_NODES, 16, 128);
    gather16<<<dim3((N_NODES + 15) / 16), dim3(256), 0, stream>>>(cnt, nbr, wgt, t2, out_f);

    // ---- dense Adj output last (overwrites CSR region) ----
    hipMemsetAsync(Adj, 0, (size_t)N_NODES * N_NODES * sizeof(float), stream);
    adj_scatter<<<dim3(eblocks), dim3(256), 0, stream>>>(tv, ti, dis, Adj);
}

// Round 14
// 1766.057 us; speedup vs baseline: 1.3269x; 1.0003x over previous
//
#include <hip/hip_runtime.h>
#include <hip/hip_bf16.h>
#include <cstddef>

#define N_NODES 10000
#define KTOP 30
#define CAP 2048     // max CSR row length
#define NBINS 4096
#define CANDCAP 512
#define NQ4 (N_NODES / 4)   // 2500 float4 per row

// ---------------- fp32 GEMM: C[M,N] = op(A[M,K] @ B[K,N] + bias) ----------------
template<int RELU, int BIAS>
__global__ __launch_bounds__(256) void gemm_rect(const float* __restrict__ A,
                                                 const float* __restrict__ B,
                                                 const float* __restrict__ bias,
                                                 float* __restrict__ C,
                                                 int M, int N, int K) {
    __shared__ float As[16][132];
    __shared__ float Bs[16][64];
    int t = threadIdx.x;
    int tx = t & 15;
    int ty = t >> 4;
    int m0 = blockIdx.y * 128;
    int n0 = blockIdx.x * 64;
    float acc[8][4];
    for (int r = 0; r < 8; r++) {
        for (int c = 0; c < 4; c++) { acc[r][c] = 0.f; }
    }
    for (int k0 = 0; k0 < K; k0 += 16) {
        for (int i = 0; i < 8; i++) {
            int idx = t + i * 256;
            int m = idx >> 4;
            int k = idx & 15;
            int gm = m0 + m;
            float v = 0.f;
            if (gm < M) { v = A[(size_t)gm * K + k0 + k]; }
            As[k][m] = v;
        }
        for (int i = 0; i < 4; i++) {
            int idx = t + i * 256;
            int k = idx >> 6;
            int n = idx & 63;
            int gn = n0 + n;
            float v = 0.f;
            if (gn < N) { v = B[(size_t)(k0 + k) * N + gn]; }
            Bs[k][n] = v;
        }
        __syncthreads();
        for (int kk = 0; kk < 16; kk++) {
            float a[8];
            float b[4];
            #pragma unroll
            for (int r = 0; r < 8; r++) { a[r] = As[kk][ty * 8 + r]; }
            #pragma unroll
            for (int c = 0; c < 4; c++) { b[c] = Bs[kk][tx * 4 + c]; }
            #pragma unroll
            for (int r = 0; r < 8; r++) {
                #pragma unroll
                for (int c = 0; c < 4; c++) {
                    acc[r][c] = fmaf(a[r], b[c], acc[r][c]);
                }
            }
        }
        __syncthreads();
    }
    for (int r = 0; r < 8; r++) {
        int gm = m0 + ty * 8 + r;
        if (gm >= M) { continue; }
        for (int c = 0; c < 4; c++) {
            int gn = n0 + tx * 4 + c;
            if (gn >= N) { continue; }
            float v = acc[r][c];
            if (BIAS) { v += bias[gn]; }
            if (RELU) { v = fmaxf(v, 0.f); }
            C[(size_t)gm * N + gn] = v;
        }
    }
}

// ---------------- row normalize, numpy-pairwise-exact semantics ----------------
__global__ __launch_bounds__(256) void rownorm_np_kernel(float* __restrict__ h) {
    __shared__ float row[256];
    __shared__ float denom_sh;
    int r = blockIdx.x;
    int t = threadIdx.x;
    float* p = h + (size_t)r * 256;
    row[t] = p[t];
    __syncthreads();
    if (t == 0) {
        float res[2];
        for (int half = 0; half < 2; half++) {
            const float* a = row + half * 128;
            float rr[8];
            #pragma unroll
            for (int j = 0; j < 8; j++) {
                rr[j] = __fmul_rn(a[j], a[j]);
            }
            for (int i = 8; i < 128; i += 8) {
                #pragma unroll
                for (int j = 0; j < 8; j++) {
                    rr[j] = __fadd_rn(rr[j], __fmul_rn(a[i + j], a[i + j]));
                }
            }
            res[half] = __fadd_rn(
                __fadd_rn(__fadd_rn(rr[0], rr[1]), __fadd_rn(rr[2], rr[3])),
                __fadd_rn(__fadd_rn(rr[4], rr[5]), __fadd_rn(rr[6], rr[7])));
        }
        float tot = __fadd_rn(res[0], res[1]);
        denom_sh = __fadd_rn(__fsqrt_rn(tot), 1e-8f);
    }
    __syncthreads();
    p[t] = __fdiv_rn(row[t], denom_sh);
}

// ---------------- S tile GEMM (NT, symmetric): S[r,j]=S[j,r]=relu(hn[r].hn[j]) ----------------
__global__ __launch_bounds__(256) void gemm_s_kernel(const float* __restrict__ hn,
                                                     float* __restrict__ S) {
    int rb = blockIdx.y * 128;
    int cb = blockIdx.x * 128;
    if (cb < rb) { return; }
    __shared__ __align__(16) float As[16][132];
    __shared__ __align__(16) float Bs[16][132];
    int t = threadIdx.x;
    int w = t >> 6;
    int lane = t & 63;
    int colf = (lane & 7) + ((w & 1) << 3);    // 0..15
    int rowf = (lane >> 3) + ((w >> 1) << 3);  // 0..15
    float acc[8][8];
    for (int r = 0; r < 8; r++) {
        for (int c = 0; c < 8; c++) { acc[r][c] = 0.f; }
    }
    int m = t & 127;
    int c0 = t >> 7;
    for (int k0 = 0; k0 < 256; k0 += 16) {
        for (int it = 0; it < 2; it++) {
            int c = c0 + 2 * it;
            int gr = rb + m;
            if (gr > N_NODES - 1) { gr = N_NODES - 1; }
            float4 va = *(const float4*)(hn + (size_t)gr * 256 + k0 + 4 * c);
            As[4 * c + 0][m] = va.x;
            As[4 * c + 1][m] = va.y;
            As[4 * c + 2][m] = va.z;
            As[4 * c + 3][m] = va.w;
            int gc = cb + m;
            if (gc > N_NODES - 1) { gc = N_NODES - 1; }
            float4 vb = *(const float4*)(hn + (size_t)gc * 256 + k0 + 4 * c);
            Bs[4 * c + 0][m] = vb.x;
            Bs[4 * c + 1][m] = vb.y;
            Bs[4 * c + 2][m] = vb.z;
            Bs[4 * c + 3][m] = vb.w;
        }
        __syncthreads();
        for (int kk = 0; kk < 16; kk++) {
            float a[8];
            float b[8];
            *(float4*)&a[0] = *(const float4*)&As[kk][rowf * 8];
            *(float4*)&a[4] = *(const float4*)&As[kk][rowf * 8 + 4];
            *(float4*)&b[0] = *(const float4*)&Bs[kk][colf * 8];
            *(float4*)&b[4] = *(const float4*)&Bs[kk][colf * 8 + 4];
            #pragma unroll
            for (int r = 0; r < 8; r++) {
                #pragma unroll
                for (int c = 0; c < 8; c++) {
                    acc[r][c] = fmaf(a[r], b[c], acc[r][c]);
                }
            }
        }
        __syncthreads();
    }
    int rr0 = rb + rowf * 8;
    int cc0 = cb + colf * 8;
    for (int r = 0; r < 8; r++) {
        int rr = rr0 + r;
        if (rr >= N_NODES) { continue; }
        float v[8];
        #pragma unroll
        for (int c = 0; c < 8; c++) { v[c] = fmaxf(acc[r][c], 0.f); }
        if (cc0 + 7 < N_NODES) {
            float* dst = S + (size_t)rr * N_NODES + cc0;
            *(float4*)dst = *(float4*)&v[0];
            *(float4*)(dst + 4) = *(float4*)&v[4];
        } else {
            for (int c = 0; c < 8; c++) {
                int cc = cc0 + c;
                if (cc < N_NODES) { S[(size_t)rr * N_NODES + cc] = v[c]; }
            }
        }
    }
    for (int c = 0; c < 8; c++) {
        int cc = cc0 + c;
        if (cc >= N_NODES) { continue; }
        float v[8];
        #pragma unroll
        for (int r = 0; r < 8; r++) { v[r] = fmaxf(acc[r][c], 0.f); }
        if (rr0 + 7 < N_NODES) {
            float* dst = S + (size_t)cc * N_NODES + rr0;
            *(float4*)dst = *(float4*)&v[0];
            *(float4*)(dst + 4) = *(float4*)&v[4];
        } else {
            for (int r = 0; r < 8; r++) {
                int rr = rr0 + r;
                if (rr < N_NODES) { S[(size_t)cc * N_NODES + rr] = v[r]; }
            }
        }
    }
}

// ---------------- radix-select top-30 per row, ties -> HIGHEST index ----------------
// All 10 row-loads per thread issued before consumption, pinned with
// sched_barrier(0) so the compiler cannot re-serialize them (r13 failure mode:
// VGPR stayed 36 => loads sunk back into the loop). Semantics unchanged.
__global__ __launch_bounds__(256) void topk_radix_kernel(float* __restrict__ S,
                                                         float* __restrict__ tv,
                                                         int* __restrict__ ti) {
    __shared__ int hist[NBINS];
    __shared__ int chunkSum[256];
    __shared__ float cv[CANDCAP];
    __shared__ int ci[CANDCAP];
    __shared__ int cntSh;
    __shared__ int thrSh;
    __shared__ float wv[4];
    __shared__ int wi[4];
    __shared__ int wq[4];
    int t = threadIdx.x;
    int r = blockIdx.x;
    float* row = S + (size_t)r * N_NODES;

    for (int b = t; b < NBINS; b += 256) { hist[b] = 0; }
    if (t == 0) { cntSh = 0; }
    __syncthreads();

    // pass 1: histogram of positives; all 10 loads in flight before consumption
    {
        float4 vv[10];
        int ok[10];
        #pragma unroll
        for (int u = 0; u < 10; u++) {
            int j4 = t + u * 256;
            ok[u] = j4 < NQ4;
            int jc = ok[u] ? j4 : (NQ4 - 1);
            vv[u] = *(const float4*)(row + 4 * jc);
        }
        __builtin_amdgcn_sched_barrier(0);
        #pragma unroll
        for (int u = 0; u < 10; u++) {
            if (!ok[u]) { continue; }
            float4 v = vv[u];
            if (v.x > 0.f) { atomicAdd(&hist[__float_as_uint(v.x) >> 18], 1); }
            if (v.y > 0.f) { atomicAdd(&hist[__float_as_uint(v.y) >> 18], 1); }
            if (v.z > 0.f) { atomicAdd(&hist[__float_as_uint(v.z) >> 18], 1); }
            if (v.w > 0.f) { atomicAdd(&hist[__float_as_uint(v.w) >> 18], 1); }
        }
    }
    __syncthreads();
    // suffix-count: find threshold bin T among positives
    int cs = 0;
    for (int b = 0; b < 16; b++) { cs += hist[t * 16 + b]; }
    chunkSum[t] = cs;
    __syncthreads();
    if (t == 0) {
        int npos = 0;
        for (int c = 0; c < 256; c++) { npos += chunkSum[c]; }
        if (npos < KTOP) {
            thrSh = -1;  // fallback
        } else {
            int cum = 0;
            int c = 255;
            for (; c >= 0; c--) {
                cum += chunkSum[c];
                if (cum >= KTOP) { break; }
            }
            int acc = cum - chunkSum[c];
            int T = c * 16;
            for (int b = c * 16 + 15; b >= c * 16; b--) {
                acc += hist[b];
                if (acc >= KTOP) { T = b; break; }
            }
            thrSh = T;
        }
    }
    __syncthreads();
    int T = thrSh;
    int ncand = 0;

    if (T >= 0) {
        // pass 2: collect candidates (positive, key >= T); same 10-deep pinned batch
        float4 vv[10];
        int ok[10];
        #pragma unroll
        for (int u = 0; u < 10; u++) {
            int j4 = t + u * 256;
            ok[u] = j4 < NQ4;
            int jc = ok[u] ? j4 : (NQ4 - 1);
            vv[u] = *(const float4*)(row + 4 * jc);
        }
        __builtin_amdgcn_sched_barrier(0);
        #pragma unroll
        for (int u = 0; u < 10; u++) {
            if (!ok[u]) { continue; }
            float4 v = vv[u];
            int base = 4 * (t + u * 256);
            float vq[4];
            vq[0] = v.x; vq[1] = v.y; vq[2] = v.z; vq[3] = v.w;
            #pragma unroll
            for (int q = 0; q < 4; q++) {
                if (vq[q] > 0.f && (int)(__float_as_uint(vq[q]) >> 18) >= T) {
                    int p = atomicAdd(&cntSh, 1);
                    if (p < CANDCAP) {
                        cv[p] = vq[q];
                        ci[p] = base + q;
                    }
                }
            }
        }
        __syncthreads();
        ncand = cntSh;
    }

    if (T < 0 || ncand > CANDCAP) {
        // exact fallback: iterative argmax over the global row (destructive; S dead after)
        for (int k = 0; k < KTOP; k++) {
            float bv = -1.f;
            int bi = -1;
            for (int j = t; j < N_NODES; j += 256) {
                float v = row[j];
                if (v >= bv) { bv = v; bi = j; }
            }
            for (int off = 32; off > 0; off >>= 1) {
                float ov = __shfl_down(bv, off, 64);
                int oi = __shfl_down(bi, off, 64);
                if (ov > bv || (ov == bv && oi > bi)) { bv = ov; bi = oi; }
            }
            if ((t & 63) == 0) { wv[t >> 6] = bv; wi[t >> 6] = bi; }
            __syncthreads();
            if (t == 0) {
                float fv = wv[0];
                int fi = wi[0];
                for (int q = 1; q < 4; q++) {
                    if (wv[q] > fv || (wv[q] == fv && wi[q] > fi)) { fv = wv[q]; fi = wi[q]; }
                }
                tv[r * KTOP + k] = fv;
                ti[r * KTOP + k] = fi;
                row[fi] = -1.f;
            }
            __syncthreads();
        }
        return;
    }

    // exact selection over candidates: (value desc, index desc)
    for (int k = 0; k < KTOP; k++) {
        float bv = -2.f;
        int bi = -1;
        int bq = -1;
        for (int q = t; q < ncand; q += 256) {
            float v = cv[q];
            int idx = ci[q];
            if (v > bv || (v == bv && idx > bi)) { bv = v; bi = idx; bq = q; }
        }
        for (int off = 32; off > 0; off >>= 1) {
            float ov = __shfl_down(bv, off, 64);
            int oi = __shfl_down(bi, off, 64);
            int oq = __shfl_down(bq, off, 64);
            if (ov > bv || (ov == bv && oi > bi)) { bv = ov; bi = oi; bq = oq; }
        }
        if ((t & 63) == 0) { wv[t >> 6] = bv; wi[t >> 6] = bi; wq[t >> 6] = bq; }
        __syncthreads();
        if (t == 0) {
            float fv = wv[0];
            int fi = wi[0];
            int fq = wq[0];
            for (int q = 1; q < 4; q++) {
                if (wv[q] > fv || (wv[q] == fv && wi[q] > fi)) {
                    fv = wv[q]; fi = wi[q]; fq = wq[q];
                }
            }
            tv[r * KTOP + k] = fv;
            ti[r * KTOP + k] = fi;
            cv[fq] = -2.f;
        }
        __syncthreads();
    }
}

// ---------------- degree accumulation ----------------
__global__ __launch_bounds__(256) void degree_kernel(const float* __restrict__ tv,
                                                     const int* __restrict__ ti,
                                                     float* __restrict__ deg) {
    int e = blockIdx.x * 256 + threadIdx.x;
    if (e >= N_NODES * KTOP) { return; }
    int i = e / KTOP;
    int j = ti[e];
    float v = 0.5f * tv[e];
    atomicAdd(deg + i, v);
    atomicAdd(deg + j, v);
}

__global__ __launch_bounds__(256) void dis_kernel(const float* __restrict__ deg,
                                                  float* __restrict__ dis) {
    int i = blockIdx.x * 256 + threadIdx.x;
    if (i < N_NODES) {
        float d = deg[i];
        dis[i] = d > 0.f ? 1.f / sqrtf(fmaxf(d, 1e-8f)) : 0.f;
    }
}

// ---------------- CSR build ----------------
__global__ __launch_bounds__(256) void csr_build(const float* __restrict__ tv,
                                                 const int* __restrict__ ti,
                                                 const float* __restrict__ dis,
                                                 int* __restrict__ cnt,
                                                 int* __restrict__ nbr,
                                                 float* __restrict__ wgt) {
    int e = blockIdx.x * 256 + threadIdx.x;
    if (e >= N_NODES * KTOP) { return; }
    int i = e / KTOP;
    int j = ti[e];
    float v = tv[e];
    float vrev = 0.f;
    bool mutual = false;
    const int* tj = ti + (size_t)j * KTOP;
    const float* tvj = tv + (size_t)j * KTOP;
    for (int k = 0; k < KTOP; k++) {
        if (tj[k] == i) { vrev = tvj[k]; mutual = true; }
    }
    float w = 0.5f * (v + vrev) * dis[i] * dis[j];
    int p = atomicAdd(cnt + i, 1);
    if (p < CAP) {
        nbr[(size_t)i * CAP + p] = j;
        wgt[(size_t)i * CAP + p] = w;
    }
    if (!mutual) {
        int p2 = atomicAdd(cnt + j, 1);
        if (p2 < CAP) {
            nbr[(size_t)j * CAP + p2] = i;
            wgt[(size_t)j * CAP + p2] = w;
        }
    }
}

// ---------------- gather SpMM, 128 channels, relu fused ----------------
__global__ __launch_bounds__(256) void gather128(const int* __restrict__ cnt,
                                                 const int* __restrict__ nbr,
                                                 const float* __restrict__ wgt,
                                                 const float* __restrict__ T,
                                                 float* __restrict__ Y) {
    int node = blockIdx.x * 2 + (threadIdx.x >> 7);
    int c = threadIdx.x & 127;
    if (node >= N_NODES) { return; }
    int n = cnt[node];
    if (n > CAP) { n = CAP; }
    const int* nb = nbr + (size_t)node * CAP;
    const float* wg = wgt + (size_t)node * CAP;
    float acc = 0.f;
    for (int k = 0; k < n; k++) {
        acc = fmaf(wg[k], T[(size_t)nb[k] * 128 + c], acc);
    }
    Y[(size_t)node * 128 + c] = fmaxf(acc, 0.f);
}

// ---------------- gather SpMM, 16 channels ----------------
__global__ __launch_bounds__(256) void gather16(const int* __restrict__ cnt,
                                                const int* __restrict__ nbr,
                                                const float* __restrict__ wgt,
                                                const float* __restrict__ T,
                                                float* __restrict__ Y) {
    int node = blockIdx.x * 16 + (threadIdx.x >> 4);
    int c = threadIdx.x & 15;
    if (node >= N_NODES) { return; }
    int n = cnt[node];
    if (n > CAP) { n = CAP; }
    const int* nb = nbr + (size_t)node * CAP;
    const float* wg = wgt + (size_t)node * CAP;
    float acc = 0.f;
    for (int k = 0; k < n; k++) {
        acc = fmaf(wg[k], T[(size_t)nb[k] * 16 + c], acc);
    }
    Y[(size_t)node * 16 + c] = acc;
}

// ---------------- Adj scatter (dense output) ----------------
__global__ __launch_bounds__(256) void adj_scatter(const float* __restrict__ tv,
                                                   const int* __restrict__ ti,
                                                   const float* __restrict__ dis,
                                                   float* __restrict__ Adj) {
    int e = blockIdx.x * 256 + threadIdx.x;
    if (e >= N_NODES * KTOP) { return; }
    int i = e / KTOP;
    int j = ti[e];
    float v = tv[e];
    float vrev = 0.f;
    const int* tj = ti + (size_t)j * KTOP;
    const float* tvj = tv + (size_t)j * KTOP;
    for (int k = 0; k < KTOP; k++) {
        if (tj[k] == i) { vrev = tvj[k]; }
    }
    float w = 0.5f * (v + vrev) * dis[i] * dis[j];
    Adj[(size_t)i * N_NODES + j] = w;
    Adj[(size_t)j * N_NODES + i] = w;
}

extern "C" void kernel_launch(void* const* d_in, const int* in_sizes, int n_in,
                              void* d_out, int out_size, void* d_ws, size_t ws_size,
                              hipStream_t stream) {
    const float* features = (const float*)d_in[0];
    const float* x   = (const float*)d_in[1];
    const float* W1  = (const float*)d_in[2];
    const float* W2  = (const float*)d_in[3];
    const float* Wg1 = (const float*)d_in[4];
    const float* bg1 = (const float*)d_in[5];
    const float* Wg2 = (const float*)d_in[6];
    const float* bg2 = (const float*)d_in[7];

    float* ws = (float*)d_ws;
    float* hbuf = ws;                         // 2,560,000 f
    float* htmp = ws + 2560000;               // 2,560,000 f
    float* tv   = ws + 5120000;               // 300,000 f
    int*   ti   = (int*)(ws + 5420000);       // 300,000 i
    float* deg  = ws + 5720000;               // 10,000 f
    float* dis  = ws + 5730000;               // 10,000 f
    float* t2   = ws + 5740000;               // 160,000 f
    int*   cnt  = (int*)(ws + 5900000);       // 10,000 i
    float* t1   = hbuf;                       // reuse
    float* y1   = htmp;                       // reuse

    float* out_f = (float*)d_out;             // 160,000 f32
    float* Adj   = out_f + 160000;            // 1e8 f32 = 400 MB
    float* Sbuf  = Adj;                       // S until topk
    int*   nbr   = (int*)Adj;                 // CSR neighbors 82 MB
    float* wgt   = (float*)(Adj + (size_t)N_NODES * CAP);  // CSR weights 82 MB

    // ---- fp32 MLP chain ----
    dim3 g1(4, 79);
    gemm_rect<1, 0><<<g1, dim3(256), 0, stream>>>(
        features, W1, (const float*)nullptr, htmp, N_NODES, 256, 256);
    gemm_rect<0, 0><<<g1, dim3(256), 0, stream>>>(
        htmp, W2, (const float*)nullptr, hbuf, N_NODES, 256, 256);
    rownorm_np_kernel<<<dim3(N_NODES), dim3(256), 0, stream>>>(hbuf);

    // ---- S (triangle + mirror), radix top-30 with highest-index ties ----
    gemm_s_kernel<<<dim3(79, 79), dim3(256), 0, stream>>>(hbuf, Sbuf);
    topk_radix_kernel<<<dim3(N_NODES), dim3(256), 0, stream>>>(Sbuf, tv, ti);

    // ---- degrees + normalization ----
    hipMemsetAsync(deg, 0, N_NODES * sizeof(float), stream);
    int eblocks = (N_NODES * KTOP + 255) / 256;
    degree_kernel<<<dim3(eblocks), dim3(256), 0, stream>>>(tv, ti, deg);
    dis_kernel<<<dim3((N_NODES + 255) / 256), dim3(256), 0, stream>>>(deg, dis);

    // ---- CSR build in the (dead) S/Adj region ----
    hipMemsetAsync(cnt, 0, N_NODES * sizeof(int), stream);
    csr_build<<<dim3(eblocks), dim3(256), 0, stream>>>(tv, ti, dis, cnt, nbr, wgt);

    // ---- GCN layers via gather SpMM ----
    gemm_rect<0, 1><<<dim3(2, 79), dim3(256), 0, stream>>>(
        x, Wg1, bg1, t1, N_NODES, 128, 256);
    gather128<<<dim3(N_NODES / 2), dim3(256), 0, stream>>>(cnt, nbr, wgt, t1, y1);
    gemm_rect<0, 1><<<dim3(1, 79), dim3(256), 0, stream>>>(
        y1, Wg2, bg2, t2, N_NODES, 16, 128);
    gather16<<<dim3((N_NODES + 15) / 16), dim3(256), 0, stream>>>(cnt, nbr, wgt, t2, out_f);

    // ---- dense Adj output last (overwrites CSR region) ----
    hipMemsetAsync(Adj, 0, (size_t)N_NODES * N_NODES * sizeof(float), stream);
    adj_scatter<<<dim3(eblocks), dim3(256), 0, stream>>>(tv, ti, dis, Adj);
}

// Round 15
// 1760.391 us; speedup vs baseline: 1.3312x; 1.0032x over previous
//
#include <hip/hip_runtime.h>
#include <hip/hip_bf16.h>
#include <cstddef>

#define N_NODES 10000
#define KTOP 30
#define CAP 2048     // max CSR row length
#define NBINS 4096
#define CANDCAP 512
#define NQ4 (N_NODES / 4)   // 2500 float4 per row

// ---------------- fp32 GEMM: C[M,N] = op(A[M,K] @ B[K,N] + bias) ----------------
template<int RELU, int BIAS>
__global__ __launch_bounds__(256) void gemm_rect(const float* __restrict__ A,
                                                 const float* __restrict__ B,
                                                 const float* __restrict__ bias,
                                                 float* __restrict__ C,
                                                 int M, int N, int K) {
    __shared__ float As[16][132];
    __shared__ float Bs[16][64];
    int t = threadIdx.x;
    int tx = t & 15;
    int ty = t >> 4;
    int m0 = blockIdx.y * 128;
    int n0 = blockIdx.x * 64;
    float acc[8][4];
    for (int r = 0; r < 8; r++) {
        for (int c = 0; c < 4; c++) { acc[r][c] = 0.f; }
    }
    for (int k0 = 0; k0 < K; k0 += 16) {
        for (int i = 0; i < 8; i++) {
            int idx = t + i * 256;
            int m = idx >> 4;
            int k = idx & 15;
            int gm = m0 + m;
            float v = 0.f;
            if (gm < M) { v = A[(size_t)gm * K + k0 + k]; }
            As[k][m] = v;
        }
        for (int i = 0; i < 4; i++) {
            int idx = t + i * 256;
            int k = idx >> 6;
            int n = idx & 63;
            int gn = n0 + n;
            float v = 0.f;
            if (gn < N) { v = B[(size_t)(k0 + k) * N + gn]; }
            Bs[k][n] = v;
        }
        __syncthreads();
        for (int kk = 0; kk < 16; kk++) {
            float a[8];
            float b[4];
            #pragma unroll
            for (int r = 0; r < 8; r++) { a[r] = As[kk][ty * 8 + r]; }
            #pragma unroll
            for (int c = 0; c < 4; c++) { b[c] = Bs[kk][tx * 4 + c]; }
            #pragma unroll
            for (int r = 0; r < 8; r++) {
                #pragma unroll
                for (int c = 0; c < 4; c++) {
                    acc[r][c] = fmaf(a[r], b[c], acc[r][c]);
                }
            }
        }
        __syncthreads();
    }
    for (int r = 0; r < 8; r++) {
        int gm = m0 + ty * 8 + r;
        if (gm >= M) { continue; }
        for (int c = 0; c < 4; c++) {
            int gn = n0 + tx * 4 + c;
            if (gn >= N) { continue; }
            float v = acc[r][c];
            if (BIAS) { v += bias[gn]; }
            if (RELU) { v = fmaxf(v, 0.f); }
            C[(size_t)gm * N + gn] = v;
        }
    }
}

// ---------------- row normalize, numpy-pairwise-exact semantics ----------------
__global__ __launch_bounds__(256) void rownorm_np_kernel(float* __restrict__ h) {
    __shared__ float row[256];
    __shared__ float denom_sh;
    int r = blockIdx.x;
    int t = threadIdx.x;
    float* p = h + (size_t)r * 256;
    row[t] = p[t];
    __syncthreads();
    if (t == 0) {
        float res[2];
        for (int half = 0; half < 2; half++) {
            const float* a = row + half * 128;
            float rr[8];
            #pragma unroll
            for (int j = 0; j < 8; j++) {
                rr[j] = __fmul_rn(a[j], a[j]);
            }
            for (int i = 8; i < 128; i += 8) {
                #pragma unroll
                for (int j = 0; j < 8; j++) {
                    rr[j] = __fadd_rn(rr[j], __fmul_rn(a[i + j], a[i + j]));
                }
            }
            res[half] = __fadd_rn(
                __fadd_rn(__fadd_rn(rr[0], rr[1]), __fadd_rn(rr[2], rr[3])),
                __fadd_rn(__fadd_rn(rr[4], rr[5]), __fadd_rn(rr[6], rr[7])));
        }
        float tot = __fadd_rn(res[0], res[1]);
        denom_sh = __fadd_rn(__fsqrt_rn(tot), 1e-8f);
    }
    __syncthreads();
    p[t] = __fdiv_rn(row[t], denom_sh);
}

// ---------------- S tile GEMM (NT, symmetric): S[r,j]=S[j,r]=relu(hn[r].hn[j]) ----------------
__global__ __launch_bounds__(256) void gemm_s_kernel(const float* __restrict__ hn,
                                                     float* __restrict__ S) {
    int rb = blockIdx.y * 128;
    int cb = blockIdx.x * 128;
    if (cb < rb) { return; }
    __shared__ __align__(16) float As[16][132];
    __shared__ __align__(16) float Bs[16][132];
    int t = threadIdx.x;
    int w = t >> 6;
    int lane = t & 63;
    int colf = (lane & 7) + ((w & 1) << 3);    // 0..15
    int rowf = (lane >> 3) + ((w >> 1) << 3);  // 0..15
    float acc[8][8];
    for (int r = 0; r < 8; r++) {
        for (int c = 0; c < 8; c++) { acc[r][c] = 0.f; }
    }
    int m = t & 127;
    int c0 = t >> 7;
    for (int k0 = 0; k0 < 256; k0 += 16) {
        for (int it = 0; it < 2; it++) {
            int c = c0 + 2 * it;
            int gr = rb + m;
            if (gr > N_NODES - 1) { gr = N_NODES - 1; }
            float4 va = *(const float4*)(hn + (size_t)gr * 256 + k0 + 4 * c);
            As[4 * c + 0][m] = va.x;
            As[4 * c + 1][m] = va.y;
            As[4 * c + 2][m] = va.z;
            As[4 * c + 3][m] = va.w;
            int gc = cb + m;
            if (gc > N_NODES - 1) { gc = N_NODES - 1; }
            float4 vb = *(const float4*)(hn + (size_t)gc * 256 + k0 + 4 * c);
            Bs[4 * c + 0][m] = vb.x;
            Bs[4 * c + 1][m] = vb.y;
            Bs[4 * c + 2][m] = vb.z;
            Bs[4 * c + 3][m] = vb.w;
        }
        __syncthreads();
        for (int kk = 0; kk < 16; kk++) {
            float a[8];
            float b[8];
            *(float4*)&a[0] = *(const float4*)&As[kk][rowf * 8];
            *(float4*)&a[4] = *(const float4*)&As[kk][rowf * 8 + 4];
            *(float4*)&b[0] = *(const float4*)&Bs[kk][colf * 8];
            *(float4*)&b[4] = *(const float4*)&Bs[kk][colf * 8 + 4];
            #pragma unroll
            for (int r = 0; r < 8; r++) {
                #pragma unroll
                for (int c = 0; c < 8; c++) {
                    acc[r][c] = fmaf(a[r], b[c], acc[r][c]);
                }
            }
        }
        __syncthreads();
    }
    int rr0 = rb + rowf * 8;
    int cc0 = cb + colf * 8;
    for (int r = 0; r < 8; r++) {
        int rr = rr0 + r;
        if (rr >= N_NODES) { continue; }
        float v[8];
        #pragma unroll
        for (int c = 0; c < 8; c++) { v[c] = fmaxf(acc[r][c], 0.f); }
        if (cc0 + 7 < N_NODES) {
            float* dst = S + (size_t)rr * N_NODES + cc0;
            *(float4*)dst = *(float4*)&v[0];
            *(float4*)(dst + 4) = *(float4*)&v[4];
        } else {
            for (int c = 0; c < 8; c++) {
                int cc = cc0 + c;
                if (cc < N_NODES) { S[(size_t)rr * N_NODES + cc] = v[c]; }
            }
        }
    }
    for (int c = 0; c < 8; c++) {
        int cc = cc0 + c;
        if (cc >= N_NODES) { continue; }
        float v[8];
        #pragma unroll
        for (int r = 0; r < 8; r++) { v[r] = fmaxf(acc[r][c], 0.f); }
        if (rr0 + 7 < N_NODES) {
            float* dst = S + (size_t)cc * N_NODES + rr0;
            *(float4*)dst = *(float4*)&v[0];
            *(float4*)(dst + 4) = *(float4*)&v[4];
        } else {
            for (int r = 0; r < 8; r++) {
                int rr = rr0 + r;
                if (rr < N_NODES) { S[(size_t)cc * N_NODES + rr] = v[r]; }
            }
        }
    }
}

// ---------------- radix-select top-30 per row, ties -> HIGHEST index ----------------
// launch_bounds(256,4): relax the VGPR budget (r13/r14 failure: allocator
// targeting max occupancy capped VGPR at 36 and re-serialized the 10-deep
// load batch). 4 blocks/CU x 10 outstanding loads/wave >> 7 blocks x 1.
__global__ __launch_bounds__(256, 4) void topk_radix_kernel(float* __restrict__ S,
                                                            float* __restrict__ tv,
                                                            int* __restrict__ ti) {
    __shared__ int hist[NBINS];
    __shared__ int chunkSum[256];
    __shared__ float cv[CANDCAP];
    __shared__ int ci[CANDCAP];
    __shared__ int cntSh;
    __shared__ int thrSh;
    __shared__ float wv[4];
    __shared__ int wi[4];
    __shared__ int wq[4];
    int t = threadIdx.x;
    int r = blockIdx.x;
    float* row = S + (size_t)r * N_NODES;

    for (int b = t; b < NBINS; b += 256) { hist[b] = 0; }
    if (t == 0) { cntSh = 0; }
    __syncthreads();

    // pass 1: histogram of positives; all 10 loads in flight before consumption
    {
        float4 vv[10];
        int ok[10];
        #pragma unroll
        for (int u = 0; u < 10; u++) {
            int j4 = t + u * 256;
            ok[u] = j4 < NQ4;
            int jc = ok[u] ? j4 : (NQ4 - 1);
            vv[u] = *(const float4*)(row + 4 * jc);
        }
        __builtin_amdgcn_sched_barrier(0);
        #pragma unroll
        for (int u = 0; u < 10; u++) {
            if (!ok[u]) { continue; }
            float4 v = vv[u];
            if (v.x > 0.f) { atomicAdd(&hist[__float_as_uint(v.x) >> 18], 1); }
            if (v.y > 0.f) { atomicAdd(&hist[__float_as_uint(v.y) >> 18], 1); }
            if (v.z > 0.f) { atomicAdd(&hist[__float_as_uint(v.z) >> 18], 1); }
            if (v.w > 0.f) { atomicAdd(&hist[__float_as_uint(v.w) >> 18], 1); }
        }
    }
    __syncthreads();
    // suffix-count: find threshold bin T among positives
    int cs = 0;
    for (int b = 0; b < 16; b++) { cs += hist[t * 16 + b]; }
    chunkSum[t] = cs;
    __syncthreads();
    if (t == 0) {
        int npos = 0;
        for (int c = 0; c < 256; c++) { npos += chunkSum[c]; }
        if (npos < KTOP) {
            thrSh = -1;  // fallback
        } else {
            int cum = 0;
            int c = 255;
            for (; c >= 0; c--) {
                cum += chunkSum[c];
                if (cum >= KTOP) { break; }
            }
            int acc = cum - chunkSum[c];
            int T = c * 16;
            for (int b = c * 16 + 15; b >= c * 16; b--) {
                acc += hist[b];
                if (acc >= KTOP) { T = b; break; }
            }
            thrSh = T;
        }
    }
    __syncthreads();
    int T = thrSh;
    int ncand = 0;

    if (T >= 0) {
        // pass 2: collect candidates (positive, key >= T); same 10-deep pinned batch
        float4 vv[10];
        int ok[10];
        #pragma unroll
        for (int u = 0; u < 10; u++) {
            int j4 = t + u * 256;
            ok[u] = j4 < NQ4;
            int jc = ok[u] ? j4 : (NQ4 - 1);
            vv[u] = *(const float4*)(row + 4 * jc);
        }
        __builtin_amdgcn_sched_barrier(0);
        #pragma unroll
        for (int u = 0; u < 10; u++) {
            if (!ok[u]) { continue; }
            float4 v = vv[u];
            int base = 4 * (t + u * 256);
            float vq[4];
            vq[0] = v.x; vq[1] = v.y; vq[2] = v.z; vq[3] = v.w;
            #pragma unroll
            for (int q = 0; q < 4; q++) {
                if (vq[q] > 0.f && (int)(__float_as_uint(vq[q]) >> 18) >= T) {
                    int p = atomicAdd(&cntSh, 1);
                    if (p < CANDCAP) {
                        cv[p] = vq[q];
                        ci[p] = base + q;
                    }
                }
            }
        }
        __syncthreads();
        ncand = cntSh;
    }

    if (T < 0 || ncand > CANDCAP) {
        // exact fallback: iterative argmax over the global row (destructive; S dead after)
        for (int k = 0; k < KTOP; k++) {
            float bv = -1.f;
            int bi = -1;
            for (int j = t; j < N_NODES; j += 256) {
                float v = row[j];
                if (v >= bv) { bv = v; bi = j; }
            }
            for (int off = 32; off > 0; off >>= 1) {
                float ov = __shfl_down(bv, off, 64);
                int oi = __shfl_down(bi, off, 64);
                if (ov > bv || (ov == bv && oi > bi)) { bv = ov; bi = oi; }
            }
            if ((t & 63) == 0) { wv[t >> 6] = bv; wi[t >> 6] = bi; }
            __syncthreads();
            if (t == 0) {
                float fv = wv[0];
                int fi = wi[0];
                for (int q = 1; q < 4; q++) {
                    if (wv[q] > fv || (wv[q] == fv && wi[q] > fi)) { fv = wv[q]; fi = wi[q]; }
                }
                tv[r * KTOP + k] = fv;
                ti[r * KTOP + k] = fi;
                row[fi] = -1.f;
            }
            __syncthreads();
        }
        return;
    }

    // exact selection over candidates: (value desc, index desc)
    for (int k = 0; k < KTOP; k++) {
        float bv = -2.f;
        int bi = -1;
        int bq = -1;
        for (int q = t; q < ncand; q += 256) {
            float v = cv[q];
            int idx = ci[q];
            if (v > bv || (v == bv && idx > bi)) { bv = v; bi = idx; bq = q; }
        }
        for (int off = 32; off > 0; off >>= 1) {
            float ov = __shfl_down(bv, off, 64);
            int oi = __shfl_down(bi, off, 64);
            int oq = __shfl_down(bq, off, 64);
            if (ov > bv || (ov == bv && oi > bi)) { bv = ov; bi = oi; bq = oq; }
        }
        if ((t & 63) == 0) { wv[t >> 6] = bv; wi[t >> 6] = bi; wq[t >> 6] = bq; }
        __syncthreads();
        if (t == 0) {
            float fv = wv[0];
            int fi = wi[0];
            int fq = wq[0];
            for (int q = 1; q < 4; q++) {
                if (wv[q] > fv || (wv[q] == fv && wi[q] > fi)) {
                    fv = wv[q]; fi = wi[q]; fq = wq[q];
                }
            }
            tv[r * KTOP + k] = fv;
            ti[r * KTOP + k] = fi;
            cv[fq] = -2.f;
        }
        __syncthreads();
    }
}

// ---------------- degree accumulation ----------------
__global__ __launch_bounds__(256) void degree_kernel(const float* __restrict__ tv,
                                                     const int* __restrict__ ti,
                                                     float* __restrict__ deg) {
    int e = blockIdx.x * 256 + threadIdx.x;
    if (e >= N_NODES * KTOP) { return; }
    int i = e / KTOP;
    int j = ti[e];
    float v = 0.5f * tv[e];
    atomicAdd(deg + i, v);
    atomicAdd(deg + j, v);
}

__global__ __launch_bounds__(256) void dis_kernel(const float* __restrict__ deg,
                                                  float* __restrict__ dis) {
    int i = blockIdx.x * 256 + threadIdx.x;
    if (i < N_NODES) {
        float d = deg[i];
        dis[i] = d > 0.f ? 1.f / sqrtf(fmaxf(d, 1e-8f)) : 0.f;
    }
}

// ---------------- CSR build ----------------
__global__ __launch_bounds__(256) void csr_build(const float* __restrict__ tv,
                                                 const int* __restrict__ ti,
                                                 const float* __restrict__ dis,
                                                 int* __restrict__ cnt,
                                                 int* __restrict__ nbr,
                                                 float* __restrict__ wgt) {
    int e = blockIdx.x * 256 + threadIdx.x;
    if (e >= N_NODES * KTOP) { return; }
    int i = e / KTOP;
    int j = ti[e];
    float v = tv[e];
    float vrev = 0.f;
    bool mutual = false;
    const int* tj = ti + (size_t)j * KTOP;
    const float* tvj = tv + (size_t)j * KTOP;
    for (int k = 0; k < KTOP; k++) {
        if (tj[k] == i) { vrev = tvj[k]; mutual = true; }
    }
    float w = 0.5f * (v + vrev) * dis[i] * dis[j];
    int p = atomicAdd(cnt + i, 1);
    if (p < CAP) {
        nbr[(size_t)i * CAP + p] = j;
        wgt[(size_t)i * CAP + p] = w;
    }
    if (!mutual) {
        int p2 = atomicAdd(cnt + j, 1);
        if (p2 < CAP) {
            nbr[(size_t)j * CAP + p2] = i;
            wgt[(size_t)j * CAP + p2] = w;
        }
    }
}

// ---------------- gather SpMM, 128 channels, relu fused ----------------
__global__ __launch_bounds__(256) void gather128(const int* __restrict__ cnt,
                                                 const int* __restrict__ nbr,
                                                 const float* __restrict__ wgt,
                                                 const float* __restrict__ T,
                                                 float* __restrict__ Y) {
    int node = blockIdx.x * 2 + (threadIdx.x >> 7);
    int c = threadIdx.x & 127;
    if (node >= N_NODES) { return; }
    int n = cnt[node];
    if (n > CAP) { n = CAP; }
    const int* nb = nbr + (size_t)node * CAP;
    const float* wg = wgt + (size_t)node * CAP;
    float acc = 0.f;
    for (int k = 0; k < n; k++) {
        acc = fmaf(wg[k], T[(size_t)nb[k] * 128 + c], acc);
    }
    Y[(size_t)node * 128 + c] = fmaxf(acc, 0.f);
}

// ---------------- gather SpMM, 16 channels ----------------
__global__ __launch_bounds__(256) void gather16(const int* __restrict__ cnt,
                                                const int* __restrict__ nbr,
                                                const float* __restrict__ wgt,
                                                const float* __restrict__ T,
                                                float* __restrict__ Y) {
    int node = blockIdx.x * 16 + (threadIdx.x >> 4);
    int c = threadIdx.x & 15;
    if (node >= N_NODES) { return; }
    int n = cnt[node];
    if (n > CAP) { n = CAP; }
    const int* nb = nbr + (size_t)node * CAP;
    const float* wg = wgt + (size_t)node * CAP;
    float acc = 0.f;
    for (int k = 0; k < n; k++) {
        acc = fmaf(wg[k], T[(size_t)nb[k] * 16 + c], acc);
    }
    Y[(size_t)node * 16 + c] = acc;
}

// ---------------- Adj scatter (dense output) ----------------
__global__ __launch_bounds__(256) void adj_scatter(const float* __restrict__ tv,
                                                   const int* __restrict__ ti,
                                                   const float* __restrict__ dis,
                                                   float* __restrict__ Adj) {
    int e = blockIdx.x * 256 + threadIdx.x;
    if (e >= N_NODES * KTOP) { return; }
    int i = e / KTOP;
    int j = ti[e];
    float v = tv[e];
    float vrev = 0.f;
    const int* tj = ti + (size_t)j * KTOP;
    const float* tvj = tv + (size_t)j * KTOP;
    for (int k = 0; k < KTOP; k++) {
        if (tj[k] == i) { vrev = tvj[k]; }
    }
    float w = 0.5f * (v + vrev) * dis[i] * dis[j];
    Adj[(size_t)i * N_NODES + j] = w;
    Adj[(size_t)j * N_NODES + i] = w;
}

extern "C" void kernel_launch(void* const* d_in, const int* in_sizes, int n_in,
                              void* d_out, int out_size, void* d_ws, size_t ws_size,
                              hipStream_t stream) {
    const float* features = (const float*)d_in[0];
    const float* x   = (const float*)d_in[1];
    const float* W1  = (const float*)d_in[2];
    const float* W2  = (const float*)d_in[3];
    const float* Wg1 = (const float*)d_in[4];
    const float* bg1 = (const float*)d_in[5];
    const float* Wg2 = (const float*)d_in[6];
    const float* bg2 = (const float*)d_in[7];

    float* ws = (float*)d_ws;
    float* hbuf = ws;                         // 2,560,000 f
    float* htmp = ws + 2560000;               // 2,560,000 f
    float* tv   = ws + 5120000;               // 300,000 f
    int*   ti   = (int*)(ws + 5420000);       // 300,000 i
    float* deg  = ws + 5720000;               // 10,000 f
    float* dis  = ws + 5730000;               // 10,000 f
    float* t2   = ws + 5740000;               // 160,000 f
    int*   cnt  = (int*)(ws + 5900000);       // 10,000 i
    float* t1   = hbuf;                       // reuse
    float* y1   = htmp;                       // reuse

    float* out_f = (float*)d_out;             // 160,000 f32
    float* Adj   = out_f + 160000;            // 1e8 f32 = 400 MB
    float* Sbuf  = Adj;                       // S until topk
    int*   nbr   = (int*)Adj;                 // CSR neighbors 82 MB
    float* wgt   = (float*)(Adj + (size_t)N_NODES * CAP);  // CSR weights 82 MB

    // ---- fp32 MLP chain ----
    dim3 g1(4, 79);
    gemm_rect<1, 0><<<g1, dim3(256), 0, stream>>>(
        features, W1, (const float*)nullptr, htmp, N_NODES, 256, 256);
    gemm_rect<0, 0><<<g1, dim3(256), 0, stream>>>(
        htmp, W2, (const float*)nullptr, hbuf, N_NODES, 256, 256);
    rownorm_np_kernel<<<dim3(N_NODES), dim3(256), 0, stream>>>(hbuf);

    // ---- S (triangle + mirror), radix top-30 with highest-index ties ----
    gemm_s_kernel<<<dim3(79, 79), dim3(256), 0, stream>>>(hbuf, Sbuf);
    topk_radix_kernel<<<dim3(N_NODES), dim3(256), 0, stream>>>(Sbuf, tv, ti);

    // ---- degrees + normalization ----
    hipMemsetAsync(deg, 0, N_NODES * sizeof(float), stream);
    int eblocks = (N_NODES * KTOP + 255) / 256;
    degree_kernel<<<dim3(eblocks), dim3(256), 0, stream>>>(tv, ti, deg);
    dis_kernel<<<dim3((N_NODES + 255) / 256), dim3(256), 0, stream>>>(deg, dis);

    // ---- CSR build in the (dead) S/Adj region ----
    hipMemsetAsync(cnt, 0, N_NODES * sizeof(int), stream);
    csr_build<<<dim3(eblocks), dim3(256), 0, stream>>>(tv, ti, dis, cnt, nbr, wgt);

    // ---- GCN layers via gather SpMM ----
    gemm_rect<0, 1><<<dim3(2, 79), dim3(256), 0, stream>>>(
        x, Wg1, bg1, t1, N_NODES, 128, 256);
    gather128<<<dim3(N_NODES / 2), dim3(256), 0, stream>>>(cnt, nbr, wgt, t1, y1);
    gemm_rect<0, 1><<<dim3(1, 79), dim3(256), 0, stream>>>(
        y1, Wg2, bg2, t2, N_NODES, 16, 128);
    gather16<<<dim3((N_NODES + 15) / 16), dim3(256), 0, stream>>>(cnt, nbr, wgt, t2, out_f);

    // ---- dense Adj output last (overwrites CSR region) ----
    hipMemsetAsync(Adj, 0, (size_t)N_NODES * N_NODES * sizeof(float), stream);
    adj_scatter<<<dim3(eblocks), dim3(256), 0, stream>>>(tv, ti, dis, Adj);
}

// Round 16
// 1628.479 us; speedup vs baseline: 1.4390x; 1.0810x over previous
//
#include <hip/hip_runtime.h>
#include <hip/hip_bf16.h>
#include <cstddef>

#define N_NODES 10000
#define KTOP 30
#define CAP 2048     // max CSR row length
#define NBINS 4096
#define CANDCAP 512
#define NQ4 (N_NODES / 4)   // 2500 float4 per row

// ---------------- fp32 GEMM: C[M,N] = op(A[M,K] @ B[K,N] + bias) ----------------
template<int RELU, int BIAS>
__global__ __launch_bounds__(256) void gemm_rect(const float* __restrict__ A,
                                                 const float* __restrict__ B,
                                                 const float* __restrict__ bias,
                                                 float* __restrict__ C,
                                                 int M, int N, int K) {
    __shared__ float As[16][132];
    __shared__ float Bs[16][64];
    int t = threadIdx.x;
    int tx = t & 15;
    int ty = t >> 4;
    int m0 = blockIdx.y * 128;
    int n0 = blockIdx.x * 64;
    float acc[8][4];
    for (int r = 0; r < 8; r++) {
        for (int c = 0; c < 4; c++) { acc[r][c] = 0.f; }
    }
    for (int k0 = 0; k0 < K; k0 += 16) {
        for (int i = 0; i < 8; i++) {
            int idx = t + i * 256;
            int m = idx >> 4;
            int k = idx & 15;
            int gm = m0 + m;
            float v = 0.f;
            if (gm < M) { v = A[(size_t)gm * K + k0 + k]; }
            As[k][m] = v;
        }
        for (int i = 0; i < 4; i++) {
            int idx = t + i * 256;
            int k = idx >> 6;
            int n = idx & 63;
            int gn = n0 + n;
            float v = 0.f;
            if (gn < N) { v = B[(size_t)(k0 + k) * N + gn]; }
            Bs[k][n] = v;
        }
        __syncthreads();
        for (int kk = 0; kk < 16; kk++) {
            float a[8];
            float b[4];
            #pragma unroll
            for (int r = 0; r < 8; r++) { a[r] = As[kk][ty * 8 + r]; }
            #pragma unroll
            for (int c = 0; c < 4; c++) { b[c] = Bs[kk][tx * 4 + c]; }
            #pragma unroll
            for (int r = 0; r < 8; r++) {
                #pragma unroll
                for (int c = 0; c < 4; c++) {
                    acc[r][c] = fmaf(a[r], b[c], acc[r][c]);
                }
            }
        }
        __syncthreads();
    }
    for (int r = 0; r < 8; r++) {
        int gm = m0 + ty * 8 + r;
        if (gm >= M) { continue; }
        for (int c = 0; c < 4; c++) {
            int gn = n0 + tx * 4 + c;
            if (gn >= N) { continue; }
            float v = acc[r][c];
            if (BIAS) { v += bias[gn]; }
            if (RELU) { v = fmaxf(v, 0.f); }
            C[(size_t)gm * N + gn] = v;
        }
    }
}

// ---------------- row normalize, numpy-pairwise-exact semantics ----------------
__global__ __launch_bounds__(256) void rownorm_np_kernel(float* __restrict__ h) {
    __shared__ float row[256];
    __shared__ float denom_sh;
    int r = blockIdx.x;
    int t = threadIdx.x;
    float* p = h + (size_t)r * 256;
    row[t] = p[t];
    __syncthreads();
    if (t == 0) {
        float res[2];
        for (int half = 0; half < 2; half++) {
            const float* a = row + half * 128;
            float rr[8];
            #pragma unroll
            for (int j = 0; j < 8; j++) {
                rr[j] = __fmul_rn(a[j], a[j]);
            }
            for (int i = 8; i < 128; i += 8) {
                #pragma unroll
                for (int j = 0; j < 8; j++) {
                    rr[j] = __fadd_rn(rr[j], __fmul_rn(a[i + j], a[i + j]));
                }
            }
            res[half] = __fadd_rn(
                __fadd_rn(__fadd_rn(rr[0], rr[1]), __fadd_rn(rr[2], rr[3])),
                __fadd_rn(__fadd_rn(rr[4], rr[5]), __fadd_rn(rr[6], rr[7])));
        }
        float tot = __fadd_rn(res[0], res[1]);
        denom_sh = __fadd_rn(__fsqrt_rn(tot), 1e-8f);
    }
    __syncthreads();
    p[t] = __fdiv_rn(row[t], denom_sh);
}

// ---------------- S tile GEMM (NT, symmetric): S[r,j]=S[j,r]=relu(hn[r].hn[j]) ----------------
__global__ __launch_bounds__(256) void gemm_s_kernel(const float* __restrict__ hn,
                                                     float* __restrict__ S) {
    int rb = blockIdx.y * 128;
    int cb = blockIdx.x * 128;
    if (cb < rb) { return; }
    __shared__ __align__(16) float As[16][132];
    __shared__ __align__(16) float Bs[16][132];
    int t = threadIdx.x;
    int w = t >> 6;
    int lane = t & 63;
    int colf = (lane & 7) + ((w & 1) << 3);    // 0..15
    int rowf = (lane >> 3) + ((w >> 1) << 3);  // 0..15
    float acc[8][8];
    for (int r = 0; r < 8; r++) {
        for (int c = 0; c < 8; c++) { acc[r][c] = 0.f; }
    }
    int m = t & 127;
    int c0 = t >> 7;
    for (int k0 = 0; k0 < 256; k0 += 16) {
        for (int it = 0; it < 2; it++) {
            int c = c0 + 2 * it;
            int gr = rb + m;
            if (gr > N_NODES - 1) { gr = N_NODES - 1; }
            float4 va = *(const float4*)(hn + (size_t)gr * 256 + k0 + 4 * c);
            As[4 * c + 0][m] = va.x;
            As[4 * c + 1][m] = va.y;
            As[4 * c + 2][m] = va.z;
            As[4 * c + 3][m] = va.w;
            int gc = cb + m;
            if (gc > N_NODES - 1) { gc = N_NODES - 1; }
            float4 vb = *(const float4*)(hn + (size_t)gc * 256 + k0 + 4 * c);
            Bs[4 * c + 0][m] = vb.x;
            Bs[4 * c + 1][m] = vb.y;
            Bs[4 * c + 2][m] = vb.z;
            Bs[4 * c + 3][m] = vb.w;
        }
        __syncthreads();
        for (int kk = 0; kk < 16; kk++) {
            float a[8];
            float b[8];
            *(float4*)&a[0] = *(const float4*)&As[kk][rowf * 8];
            *(float4*)&a[4] = *(const float4*)&As[kk][rowf * 8 + 4];
            *(float4*)&b[0] = *(const float4*)&Bs[kk][colf * 8];
            *(float4*)&b[4] = *(const float4*)&Bs[kk][colf * 8 + 4];
            #pragma unroll
            for (int r = 0; r < 8; r++) {
                #pragma unroll
                for (int c = 0; c < 8; c++) {
                    acc[r][c] = fmaf(a[r], b[c], acc[r][c]);
                }
            }
        }
        __syncthreads();
    }
    int rr0 = rb + rowf * 8;
    int cc0 = cb + colf * 8;
    for (int r = 0; r < 8; r++) {
        int rr = rr0 + r;
        if (rr >= N_NODES) { continue; }
        float v[8];
        #pragma unroll
        for (int c = 0; c < 8; c++) { v[c] = fmaxf(acc[r][c], 0.f); }
        if (cc0 + 7 < N_NODES) {
            float* dst = S + (size_t)rr * N_NODES + cc0;
            *(float4*)dst = *(float4*)&v[0];
            *(float4*)(dst + 4) = *(float4*)&v[4];
        } else {
            for (int c = 0; c < 8; c++) {
                int cc = cc0 + c;
                if (cc < N_NODES) { S[(size_t)rr * N_NODES + cc] = v[c]; }
            }
        }
    }
    for (int c = 0; c < 8; c++) {
        int cc = cc0 + c;
        if (cc >= N_NODES) { continue; }
        float v[8];
        #pragma unroll
        for (int r = 0; r < 8; r++) { v[r] = fmaxf(acc[r][c], 0.f); }
        if (rr0 + 7 < N_NODES) {
            float* dst = S + (size_t)cc * N_NODES + rr0;
            *(float4*)dst = *(float4*)&v[0];
            *(float4*)(dst + 4) = *(float4*)&v[4];
        } else {
            for (int r = 0; r < 8; r++) {
                int rr = rr0 + r;
                if (rr < N_NODES) { S[(size_t)cc * N_NODES + rr] = v[r]; }
            }
        }
    }
}

// ---------------- radix-select top-30 per row, ties -> HIGHEST index ----------------
// Barrier-minimal: histogram + collection use all 4 waves; threshold scan and
// final selection run wave-synchronously on wave 0 (no __syncthreads in the
// 30-iteration loop; intra-wave LDS write->read is program-ordered).
__global__ __launch_bounds__(256) void topk_radix_kernel(float* __restrict__ S,
                                                         float* __restrict__ tv,
                                                         int* __restrict__ ti) {
    __shared__ int hist[NBINS];
    __shared__ int chunkSum[64];
    __shared__ float cv[CANDCAP];
    __shared__ int ci[CANDCAP];
    __shared__ int cntSh;
    __shared__ int thrSh;
    __shared__ float wv[4];
    __shared__ int wi[4];
    int t = threadIdx.x;
    int r = blockIdx.x;
    float* row = S + (size_t)r * N_NODES;

    for (int b = t; b < NBINS; b += 256) { hist[b] = 0; }
    if (t == 0) { cntSh = 0; }
    __syncthreads();

    // pass 1: histogram of positives (all waves), 10-deep strided loads
    {
        float4 vv[10];
        int ok[10];
        #pragma unroll
        for (int u = 0; u < 10; u++) {
            int j4 = t + u * 256;
            ok[u] = j4 < NQ4;
            int jc = ok[u] ? j4 : (NQ4 - 1);
            vv[u] = *(const float4*)(row + 4 * jc);
        }
        #pragma unroll
        for (int u = 0; u < 10; u++) {
            if (!ok[u]) { continue; }
            float4 v = vv[u];
            if (v.x > 0.f) { atomicAdd(&hist[__float_as_uint(v.x) >> 18], 1); }
            if (v.y > 0.f) { atomicAdd(&hist[__float_as_uint(v.y) >> 18], 1); }
            if (v.z > 0.f) { atomicAdd(&hist[__float_as_uint(v.z) >> 18], 1); }
            if (v.w > 0.f) { atomicAdd(&hist[__float_as_uint(v.w) >> 18], 1); }
        }
    }
    __syncthreads();

    // threshold scan: wave 0 only, wave-synchronous
    if (t < 64) {
        int cs = 0;
        for (int b = 0; b < 64; b++) { cs += hist[t * 64 + b]; }
        chunkSum[t] = cs;
        if (t == 0) {
            int npos = 0;
            for (int c = 0; c < 64; c++) { npos += chunkSum[c]; }
            if (npos < KTOP) {
                thrSh = -1;  // fallback
            } else {
                int cum = 0;
                int c = 63;
                for (; c >= 0; c--) {
                    cum += chunkSum[c];
                    if (cum >= KTOP) { break; }
                }
                int acc = cum - chunkSum[c];
                int T = c * 64;
                for (int b = c * 64 + 63; b >= c * 64; b--) {
                    acc += hist[b];
                    if (acc >= KTOP) { T = b; break; }
                }
                thrSh = T;
            }
        }
    }
    __syncthreads();
    int T = thrSh;

    if (T >= 0) {
        // pass 2: collect candidates (positive, key >= T); all waves, L2-warm
        float4 vv[10];
        int ok[10];
        #pragma unroll
        for (int u = 0; u < 10; u++) {
            int j4 = t + u * 256;
            ok[u] = j4 < NQ4;
            int jc = ok[u] ? j4 : (NQ4 - 1);
            vv[u] = *(const float4*)(row + 4 * jc);
        }
        #pragma unroll
        for (int u = 0; u < 10; u++) {
            if (!ok[u]) { continue; }
            float4 v = vv[u];
            int base = 4 * (t + u * 256);
            float vq[4];
            vq[0] = v.x; vq[1] = v.y; vq[2] = v.z; vq[3] = v.w;
            #pragma unroll
            for (int q = 0; q < 4; q++) {
                if (vq[q] > 0.f && (int)(__float_as_uint(vq[q]) >> 18) >= T) {
                    int p = atomicAdd(&cntSh, 1);
                    if (p < CANDCAP) {
                        cv[p] = vq[q];
                        ci[p] = base + q;
                    }
                }
            }
        }
    }
    __syncthreads();
    int ncand = cntSh;

    if (T < 0 || ncand > CANDCAP) {
        // exact fallback: block-wide iterative argmax over the global row
        for (int k = 0; k < KTOP; k++) {
            float bv = -1.f;
            int bi = -1;
            for (int j = t; j < N_NODES; j += 256) {
                float v = row[j];
                if (v >= bv) { bv = v; bi = j; }
            }
            for (int off = 32; off > 0; off >>= 1) {
                float ov = __shfl_down(bv, off, 64);
                int oi = __shfl_down(bi, off, 64);
                if (ov > bv || (ov == bv && oi > bi)) { bv = ov; bi = oi; }
            }
            if ((t & 63) == 0) { wv[t >> 6] = bv; wi[t >> 6] = bi; }
            __syncthreads();
            if (t == 0) {
                float fv = wv[0];
                int fi = wi[0];
                for (int q = 1; q < 4; q++) {
                    if (wv[q] > fv || (wv[q] == fv && wi[q] > fi)) { fv = wv[q]; fi = wi[q]; }
                }
                tv[r * KTOP + k] = fv;
                ti[r * KTOP + k] = fi;
                row[fi] = -1.f;
            }
            __syncthreads();
        }
        return;
    }

    // selection: wave 0 only, barrier-free; (value desc, index desc)
    if (t < 64) {
        for (int k = 0; k < KTOP; k++) {
            float bv = -2.f;
            int bi = -1;
            int bq = -1;
            for (int q = t; q < ncand; q += 64) {
                float v = cv[q];
                int idx = ci[q];
                if (v > bv || (v == bv && idx > bi)) { bv = v; bi = idx; bq = q; }
            }
            for (int m = 32; m > 0; m >>= 1) {
                float ov = __shfl_xor(bv, m, 64);
                int oi = __shfl_xor(bi, m, 64);
                int oq = __shfl_xor(bq, m, 64);
                if (ov > bv || (ov == bv && oi > bi)) { bv = ov; bi = oi; bq = oq; }
            }
            // all lanes agree on winner
            if (t == 0) {
                tv[r * KTOP + k] = bv;
                ti[r * KTOP + k] = bi;
                cv[bq] = -2.f;
            }
        }
    }
}

// ---------------- degree accumulation ----------------
__global__ __launch_bounds__(256) void degree_kernel(const float* __restrict__ tv,
                                                     const int* __restrict__ ti,
                                                     float* __restrict__ deg) {
    int e = blockIdx.x * 256 + threadIdx.x;
    if (e >= N_NODES * KTOP) { return; }
    int i = e / KTOP;
    int j = ti[e];
    float v = 0.5f * tv[e];
    atomicAdd(deg + i, v);
    atomicAdd(deg + j, v);
}

__global__ __launch_bounds__(256) void dis_kernel(const float* __restrict__ deg,
                                                  float* __restrict__ dis) {
    int i = blockIdx.x * 256 + threadIdx.x;
    if (i < N_NODES) {
        float d = deg[i];
        dis[i] = d > 0.f ? 1.f / sqrtf(fmaxf(d, 1e-8f)) : 0.f;
    }
}

// ---------------- CSR build ----------------
__global__ __launch_bounds__(256) void csr_build(const float* __restrict__ tv,
                                                 const int* __restrict__ ti,
                                                 const float* __restrict__ dis,
                                                 int* __restrict__ cnt,
                                                 int* __restrict__ nbr,
                                                 float* __restrict__ wgt) {
    int e = blockIdx.x * 256 + threadIdx.x;
    if (e >= N_NODES * KTOP) { return; }
    int i = e / KTOP;
    int j = ti[e];
    float v = tv[e];
    float vrev = 0.f;
    bool mutual = false;
    const int* tj = ti + (size_t)j * KTOP;
    const float* tvj = tv + (size_t)j * KTOP;
    for (int k = 0; k < KTOP; k++) {
        if (tj[k] == i) { vrev = tvj[k]; mutual = true; }
    }
    float w = 0.5f * (v + vrev) * dis[i] * dis[j];
    int p = atomicAdd(cnt + i, 1);
    if (p < CAP) {
        nbr[(size_t)i * CAP + p] = j;
        wgt[(size_t)i * CAP + p] = w;
    }
    if (!mutual) {
        int p2 = atomicAdd(cnt + j, 1);
        if (p2 < CAP) {
            nbr[(size_t)j * CAP + p2] = i;
            wgt[(size_t)j * CAP + p2] = w;
        }
    }
}

// ---------------- gather SpMM, 128 channels, relu fused ----------------
__global__ __launch_bounds__(256) void gather128(const int* __restrict__ cnt,
                                                 const int* __restrict__ nbr,
                                                 const float* __restrict__ wgt,
                                                 const float* __restrict__ T,
                                                 float* __restrict__ Y) {
    int node = blockIdx.x * 2 + (threadIdx.x >> 7);
    int c = threadIdx.x & 127;
    if (node >= N_NODES) { return; }
    int n = cnt[node];
    if (n > CAP) { n = CAP; }
    const int* nb = nbr + (size_t)node * CAP;
    const float* wg = wgt + (size_t)node * CAP;
    float acc = 0.f;
    for (int k = 0; k < n; k++) {
        acc = fmaf(wg[k], T[(size_t)nb[k] * 128 + c], acc);
    }
    Y[(size_t)node * 128 + c] = fmaxf(acc, 0.f);
}

// ---------------- gather SpMM, 16 channels ----------------
__global__ __launch_bounds__(256) void gather16(const int* __restrict__ cnt,
                                                const int* __restrict__ nbr,
                                                const float* __restrict__ wgt,
                                                const float* __restrict__ T,
                                                float* __restrict__ Y) {
    int node = blockIdx.x * 16 + (threadIdx.x >> 4);
    int c = threadIdx.x & 15;
    if (node >= N_NODES) { return; }
    int n = cnt[node];
    if (n > CAP) { n = CAP; }
    const int* nb = nbr + (size_t)node * CAP;
    const float* wg = wgt + (size_t)node * CAP;
    float acc = 0.f;
    for (int k = 0; k < n; k++) {
        acc = fmaf(wg[k], T[(size_t)nb[k] * 16 + c], acc);
    }
    Y[(size_t)node * 16 + c] = acc;
}

// ---------------- Adj scatter (dense output) ----------------
__global__ __launch_bounds__(256) void adj_scatter(const float* __restrict__ tv,
                                                   const int* __restrict__ ti,
                                                   const float* __restrict__ dis,
                                                   float* __restrict__ Adj) {
    int e = blockIdx.x * 256 + threadIdx.x;
    if (e >= N_NODES * KTOP) { return; }
    int i = e / KTOP;
    int j = ti[e];
    float v = tv[e];
    float vrev = 0.f;
    const int* tj = ti + (size_t)j * KTOP;
    const float* tvj = tv + (size_t)j * KTOP;
    for (int k = 0; k < KTOP; k++) {
        if (tj[k] == i) { vrev = tvj[k]; }
    }
    float w = 0.5f * (v + vrev) * dis[i] * dis[j];
    Adj[(size_t)i * N_NODES + j] = w;
    Adj[(size_t)j * N_NODES + i] = w;
}

extern "C" void kernel_launch(void* const* d_in, const int* in_sizes, int n_in,
                              void* d_out, int out_size, void* d_ws, size_t ws_size,
                              hipStream_t stream) {
    const float* features = (const float*)d_in[0];
    const float* x   = (const float*)d_in[1];
    const float* W1  = (const float*)d_in[2];
    const float* W2  = (const float*)d_in[3];
    const float* Wg1 = (const float*)d_in[4];
    const float* bg1 = (const float*)d_in[5];
    const float* Wg2 = (const float*)d_in[6];
    const float* bg2 = (const float*)d_in[7];

    float* ws = (float*)d_ws;
    float* hbuf = ws;                         // 2,560,000 f
    float* htmp = ws + 2560000;               // 2,560,000 f
    float* tv   = ws + 5120000;               // 300,000 f
    int*   ti   = (int*)(ws + 5420000);       // 300,000 i
    float* deg  = ws + 5720000;               // 10,000 f
    float* dis  = ws + 5730000;               // 10,000 f
    float* t2   = ws + 5740000;               // 160,000 f
    int*   cnt  = (int*)(ws + 5900000);       // 10,000 i
    float* t1   = hbuf;                       // reuse
    float* y1   = htmp;                       // reuse

    float* out_f = (float*)d_out;             // 160,000 f32
    float* Adj   = out_f + 160000;            // 1e8 f32 = 400 MB
    float* Sbuf  = Adj;                       // S until topk
    int*   nbr   = (int*)Adj;                 // CSR neighbors 82 MB
    float* wgt   = (float*)(Adj + (size_t)N_NODES * CAP);  // CSR weights 82 MB

    // ---- fp32 MLP chain ----
    dim3 g1(4, 79);
    gemm_rect<1, 0><<<g1, dim3(256), 0, stream>>>(
        features, W1, (const float*)nullptr, htmp, N_NODES, 256, 256);
    gemm_rect<0, 0><<<g1, dim3(256), 0, stream>>>(
        htmp, W2, (const float*)nullptr, hbuf, N_NODES, 256, 256);
    rownorm_np_kernel<<<dim3(N_NODES), dim3(256), 0, stream>>>(hbuf);

    // ---- S (triangle + mirror), radix top-30 with highest-index ties ----
    gemm_s_kernel<<<dim3(79, 79), dim3(256), 0, stream>>>(hbuf, Sbuf);
    topk_radix_kernel<<<dim3(N_NODES), dim3(256), 0, stream>>>(Sbuf, tv, ti);

    // ---- degrees + normalization ----
    hipMemsetAsync(deg, 0, N_NODES * sizeof(float), stream);
    int eblocks = (N_NODES * KTOP + 255) / 256;
    degree_kernel<<<dim3(eblocks), dim3(256), 0, stream>>>(tv, ti, deg);
    dis_kernel<<<dim3((N_NODES + 255) / 256), dim3(256), 0, stream>>>(deg, dis);

    // ---- CSR build in the (dead) S/Adj region ----
    hipMemsetAsync(cnt, 0, N_NODES * sizeof(int), stream);
    csr_build<<<dim3(eblocks), dim3(256), 0, stream>>>(tv, ti, dis, cnt, nbr, wgt);

    // ---- GCN layers via gather SpMM ----
    gemm_rect<0, 1><<<dim3(2, 79), dim3(256), 0, stream>>>(
        x, Wg1, bg1, t1, N_NODES, 128, 256);
    gather128<<<dim3(N_NODES / 2), dim3(256), 0, stream>>>(cnt, nbr, wgt, t1, y1);
    gemm_rect<0, 1><<<dim3(1, 79), dim3(256), 0, stream>>>(
        y1, Wg2, bg2, t2, N_NODES, 16, 128);
    gather16<<<dim3((N_NODES + 15) / 16), dim3(256), 0, stream>>>(cnt, nbr, wgt, t2, out_f);

    // ---- dense Adj output last (overwrites CSR region) ----
    hipMemsetAsync(Adj, 0, (size_t)N_NODES * N_NODES * sizeof(float), stream);
    adj_scatter<<<dim3(eblocks), dim3(256), 0, stream>>>(tv, ti, dis, Adj);
}